// Round 3
// baseline (585.565 us; speedup 1.0000x reference)
//
#include <hip/hip_runtime.h>
#include <stdint.h>

#define HD 2048
#define FD 1024
#define NE 16
#define NPAIR 8192
#define BM 256
#define MAXT 48
#define LDK 40   // 32 el + 8 pad: 80 B row stride, 16B-aligned for b128, 2-way-free banks

typedef short bf16x8 __attribute__((ext_vector_type(8)));
typedef float f32x4 __attribute__((ext_vector_type(4)));
typedef unsigned short u16;

static __device__ __forceinline__ u16 f2bf(float f) {
  uint32_t u = __float_as_uint(f);
  u += 0x7FFFu + ((u >> 16) & 1u);
  return (u16)(u >> 16);
}

// Scale-folded byte tables for e2m1 -> bf16 dequant via v_perm.
struct DqTab { uint32_t hA, hB, lA, lB; };

static __device__ __forceinline__ DqTab make_tab(uint32_t sbits) {
  int n = (int)(sbits >> 23) - 127;
  int q = n >> 1;
  uint32_t r = (uint32_t)(n & 1);
  uint32_t mq = (uint32_t)(-q);
  uint32_t sub1 = mq * 0x01010100u;  // entry 0 (zero) untouched
  uint32_t subA = mq * 0x01010101u;
  DqTab t;
  t.hA = (r ? 0x40403F00u : 0x3F3F3F00u) - sub1;
  t.hB = (r ? 0x41414040u : 0x40404040u) - subA;
  t.lA = r ? 0x40008000u : 0xC0800000u;
  t.lB = r ? 0x4000C080u : 0xC0804000u;
  return t;
}

// p: 4 packed fp4 bytes (8 values, low nibble first) -> 4 dwords of bf16 pairs
static __device__ __forceinline__ void dq8(uint32_t p, const DqTab& t, uint32_t* d) {
  uint32_t a = p & 0x0F0F0F0Fu;
  uint32_t b = (p >> 4) & 0x0F0F0F0Fu;
  uint32_t x0 = __builtin_amdgcn_perm(b, a, 0x05010400u);
  uint32_t x1 = __builtin_amdgcn_perm(b, a, 0x07030602u);
  uint32_t m0 = x0 & 0x07070707u;
  uint32_t m1 = x1 & 0x07070707u;
  uint32_t h0 = __builtin_amdgcn_perm(t.hB, t.hA, m0) | ((x0 & 0x08080808u) << 4);
  uint32_t h1 = __builtin_amdgcn_perm(t.hB, t.hA, m1) | ((x1 & 0x08080808u) << 4);
  uint32_t l0 = __builtin_amdgcn_perm(t.lB, t.lA, m0);
  uint32_t l1 = __builtin_amdgcn_perm(t.lB, t.lA, m1);
  d[0] = __builtin_amdgcn_perm(h0, l0, 0x05010400u);
  d[1] = __builtin_amdgcn_perm(h0, l0, 0x07030602u);
  d[2] = __builtin_amdgcn_perm(h1, l1, 0x05010400u);
  d[3] = __builtin_amdgcn_perm(h1, l1, 0x07030602u);
}

static __device__ __forceinline__ uint32_t pack4(int4 v) {
  return (uint32_t)(v.x & 0xFF) | ((uint32_t)(v.y & 0xFF) << 8) |
         ((uint32_t)(v.z & 0xFF) << 16) | ((uint32_t)v.w << 24);
}

__global__ void cast_kernel(const float* __restrict__ x, u16* __restrict__ xb) {
  int i = blockIdx.x * 256 + threadIdx.x;
  float4 v = ((const float4*)x)[i];
  ushort4 o;
  o.x = f2bf(v.x); o.y = f2bf(v.y); o.z = f2bf(v.z); o.w = f2bf(v.w);
  ((ushort4*)xb)[i] = o;
}

__global__ void zero_kernel(float4* __restrict__ out) {
  out[blockIdx.x * 256 + threadIdx.x] = float4{0.f, 0.f, 0.f, 0.f};
}

__global__ void route_kernel(const int* __restrict__ ids, const float* __restrict__ tw,
                             int* __restrict__ rows, float* __restrict__ rw,
                             int* __restrict__ te, int* __restrict__ pidx) {
  __shared__ int cnt[NE], base[NE], run[NE];
  int tid = threadIdx.x;
  if (tid < NE) { cnt[tid] = 0; run[tid] = 0; }
  __syncthreads();
  for (int i = tid; i < NPAIR; i += 256) atomicAdd(&cnt[ids[i]], 1);
  __syncthreads();
  if (tid == 0) {
    int cum = 0;
    for (int e = 0; e < NE; ++e) {
      base[e] = cum;
      int nt = (cnt[e] + BM - 1) >> 8;
      for (int j = 0; j < nt; ++j) te[(cum >> 8) + j] = e;
      cum += nt << 8;
    }
    for (int t = cum >> 8; t < MAXT; ++t) te[t] = -1;
  }
  __syncthreads();
  for (int i = tid; i < MAXT * BM; i += 256) {
    rows[i] = -1;
    rw[i] = 0.f;
    if (pidx) pidx[i] = -1;
  }
  __syncthreads();
  for (int i = tid; i < NPAIR; i += 256) {
    int e = ids[i];
    int p = base[e] + atomicAdd(&run[e], 1);
    rows[p] = i >> 2;
    rw[p] = tw[i];
    if (pidx) pidx[p] = i;
  }
}

// gate_up GEMM + SwiGLU + routing weight -> act (bf16). BM=256, BN=64+64, BK=32.
// Double-buffered LDS, ONE barrier per K-step.
// B (cold HBM stream) register-prefetched TWO K-steps ahead (2-stage, unrolled x2);
// A (L3-resident) prefetched one step ahead.
__global__ __launch_bounds__(256, 2) void gemm1_kernel(
    const u16* __restrict__ xb, const int* __restrict__ gup32,
    const uint32_t* __restrict__ gus, const int* __restrict__ rows,
    const float* __restrict__ rw, const int* __restrict__ te,
    u16* __restrict__ act) {
  const int tile = blockIdx.y;
  const int e = te[tile];
  if (e < 0) return;
  const int f0 = blockIdx.x * 64;

  __shared__ u16 sA[2][BM * LDK];
  __shared__ u16 sBg[2][64 * LDK];
  __shared__ u16 sBu[2][64 * LDK];
  __shared__ int rows_s[BM];
  __shared__ float rw_s[BM];

  const int tid = threadIdx.x;
  rows_s[tid] = rows[tile * BM + tid];
  rw_s[tid] = rw[tile * BM + tid];
  __syncthreads();

  int arow = rows_s[tid];
  arow = arow < 0 ? 0 : arow;
  const u16* aptr = xb + (size_t)arow * HD;
  const int lofsA = tid * LDK;

  const int bn = (tid & 127) >> 1;
  const int isUp = tid >> 7;
  const int o = isUp * 1024 + f0 + bn;
  const int skh = tid & 1;
  const int* bptr = gup32 + (size_t)(e * 2048 + o) * (HD / 2) + skh * 8;
  const uint32_t* sptr = gus + (size_t)(e * 2048 + o) * (HD / 32);
  const int lofsB = bn * LDK + skh * 16;

  const int lane = tid & 63;
  const int w = tid >> 6;
  const int q = lane >> 4, c = lane & 15;

  f32x4 Cg[4][4], Cu[4][4];
#pragma unroll
  for (int s = 0; s < 4; ++s)
#pragma unroll
    for (int t2 = 0; t2 < 4; ++t2) {
      Cg[s][t2] = f32x4{0.f, 0.f, 0.f, 0.f};
      Cu[s][t2] = f32x4{0.f, 0.f, 0.f, 0.f};
    }

  // 2-stage B prefetch registers: even-indexed K-steps live in (ebw0,ebw1,ebs),
  // odd-indexed in (obw0,obw1,obs).
  int4 ebw0, ebw1, obw0, obw1;
  uint32_t ebs, obs;

  // prologue: stage K-step 0 into buffer 0; load B(1) into the odd stage
  {
    uint4 a0 = *(const uint4*)(aptr);
    uint4 a1 = *(const uint4*)(aptr + 8);
    uint4 a2 = *(const uint4*)(aptr + 16);
    uint4 a3 = *(const uint4*)(aptr + 24);
    int4 w0 = *(const int4*)(bptr);
    int4 w1 = *(const int4*)(bptr + 4);
    uint32_t sb = sptr[0];
    DqTab t = make_tab(sb);
    uint32_t d0[4], d1[4];
    dq8(pack4(w0), t, d0);
    dq8(pack4(w1), t, d1);
    u16* sAp = &sA[0][lofsA];
    *(uint4*)sAp = a0;
    *(uint4*)(sAp + 8) = a1;
    *(uint4*)(sAp + 16) = a2;
    *(uint4*)(sAp + 24) = a3;
    u16* sBp = (isUp ? sBu[0] : sBg[0]) + lofsB;
    *(uint4*)sBp = make_uint4(d0[0], d0[1], d0[2], d0[3]);
    *(uint4*)(sBp + 8) = make_uint4(d1[0], d1[1], d1[2], d1[3]);
    obw0 = *(const int4*)(bptr + 16);
    obw1 = *(const int4*)(bptr + 20);
    obs = sptr[1];
  }

  // Per half-iteration: consume B(KK+1) from stage NBI (loaded 1 iter ago),
  // issue B(KK+2) into stage NBO (consumed next iter). NSTEP=64.
#define G1_HALF(KK, P, NBI0, NBI1, NSI, NBO0, NBO1, NSO)                       \
  {                                                                            \
    __syncthreads();                                                           \
    uint4 na0, na1, na2, na3;                                                  \
    if ((KK) < 63) {                                                           \
      const u16* ap = aptr + ((KK) + 1) * 32;                                  \
      na0 = *(const uint4*)(ap);                                               \
      na1 = *(const uint4*)(ap + 8);                                           \
      na2 = *(const uint4*)(ap + 16);                                          \
      na3 = *(const uint4*)(ap + 24);                                          \
    }                                                                          \
    if ((KK) < 62) {                                                           \
      const int* bp = bptr + ((KK) + 2) * 16;                                  \
      NBO0 = *(const int4*)(bp);                                               \
      NBO1 = *(const int4*)(bp + 4);                                           \
      NSO = sptr[(KK) + 2];                                                    \
    }                                                                          \
    bf16x8 af[4], bg[4], bu[4];                                                \
    _Pragma("unroll")                                                          \
    for (int s = 0; s < 4; ++s)                                                \
      af[s] = *(const bf16x8*)&sA[P][(w * 64 + s * 16 + c) * LDK + q * 8];     \
    _Pragma("unroll")                                                          \
    for (int t2 = 0; t2 < 4; ++t2) {                                           \
      bg[t2] = *(const bf16x8*)&sBg[P][(t2 * 16 + c) * LDK + q * 8];           \
      bu[t2] = *(const bf16x8*)&sBu[P][(t2 * 16 + c) * LDK + q * 8];           \
    }                                                                          \
    _Pragma("unroll")                                                          \
    for (int s = 0; s < 4; ++s)                                                \
      _Pragma("unroll")                                                        \
      for (int t2 = 0; t2 < 4; ++t2) {                                         \
        Cg[s][t2] = __builtin_amdgcn_mfma_f32_16x16x32_bf16(af[s], bg[t2], Cg[s][t2], 0, 0, 0); \
        Cu[s][t2] = __builtin_amdgcn_mfma_f32_16x16x32_bf16(af[s], bu[t2], Cu[s][t2], 0, 0, 0); \
      }                                                                        \
    if ((KK) < 63) {                                                           \
      DqTab t = make_tab(NSI);                                                 \
      uint32_t d0[4], d1[4];                                                   \
      dq8(pack4(NBI0), t, d0);                                                 \
      dq8(pack4(NBI1), t, d1);                                                 \
      u16* sAp = &sA[(P) ^ 1][lofsA];                                          \
      *(uint4*)sAp = na0;                                                      \
      *(uint4*)(sAp + 8) = na1;                                                \
      *(uint4*)(sAp + 16) = na2;                                               \
      *(uint4*)(sAp + 24) = na3;                                               \
      u16* sBp = (isUp ? sBu[(P) ^ 1] : sBg[(P) ^ 1]) + lofsB;                 \
      *(uint4*)sBp = make_uint4(d0[0], d0[1], d0[2], d0[3]);                   \
      *(uint4*)(sBp + 8) = make_uint4(d1[0], d1[1], d1[2], d1[3]);             \
    }                                                                          \
  }

  for (int kkp = 0; kkp < 32; ++kkp) {
    const int kk0 = kkp * 2;
    G1_HALF(kk0, 0, obw0, obw1, obs, ebw0, ebw1, ebs)
    G1_HALF(kk0 + 1, 1, ebw0, ebw1, ebs, obw0, obw1, obs)
  }
#undef G1_HALF

#pragma unroll
  for (int s = 0; s < 4; ++s) {
    const int mlb = w * 64 + s * 16 + q * 4;
#pragma unroll
    for (int t2 = 0; t2 < 4; ++t2) {
      const int fg = f0 + t2 * 16 + c;
#pragma unroll
      for (int r = 0; r < 4; ++r) {
        const int ml = mlb + r;
        float g = Cg[s][t2][r];
        float u = Cu[s][t2][r];
        float aval = g / (1.f + __expf(-g)) * u * rw_s[ml];
        act[(size_t)(tile * BM + ml) * FD + fg] = f2bf(aval);
      }
    }
  }
}

// down GEMM. BM=256, BN=128, BK=32, double-buffered, 2-deep B prefetch.
// Epilogue: if pout != null, write non-overlapping f32 partials to pout[pair, HD]
// (no atomics; finalize kernel reduces the 4 pairs/token). Else atomicAdd into out.
__global__ __launch_bounds__(256, 2) void gemm2_kernel(
    const u16* __restrict__ act, const int* __restrict__ dwn32,
    const uint32_t* __restrict__ dsc, const int* __restrict__ rows,
    const int* __restrict__ pidx, const int* __restrict__ te,
    float* __restrict__ out, float* __restrict__ pout) {
  const int tile = blockIdx.y;
  const int e = te[tile];
  if (e < 0) return;
  const int h0 = blockIdx.x * 128;

  __shared__ u16 sA[2][BM * LDK];
  __shared__ u16 sB[2][128 * LDK];
  __shared__ int rows_s[BM];
  __shared__ int pidx_s[BM];

  const int tid = threadIdx.x;
  rows_s[tid] = rows[tile * BM + tid];
  pidx_s[tid] = pout ? pidx[tile * BM + tid] : -1;
  __syncthreads();

  const u16* aptr = act + (size_t)(tile * BM + tid) * FD;
  const int lofsA = tid * LDK;

  const int bn = tid >> 1;
  const int skh = tid & 1;
  const int* bptr = dwn32 + (size_t)(e * 2048 + h0 + bn) * (FD / 2) + skh * 8;
  const uint32_t* sptr = dsc + (size_t)(e * 2048 + h0 + bn) * (FD / 32);
  const int lofsB = bn * LDK + skh * 16;

  const int lane = tid & 63;
  const int w = tid >> 6;
  const int q = lane >> 4, c = lane & 15;

  f32x4 Cd[4][8];
#pragma unroll
  for (int s = 0; s < 4; ++s)
#pragma unroll
    for (int t2 = 0; t2 < 8; ++t2) Cd[s][t2] = f32x4{0.f, 0.f, 0.f, 0.f};

  int4 ebw0, ebw1, obw0, obw1;
  uint32_t ebs, obs;

  {
    uint4 a0 = *(const uint4*)(aptr);
    uint4 a1 = *(const uint4*)(aptr + 8);
    uint4 a2 = *(const uint4*)(aptr + 16);
    uint4 a3 = *(const uint4*)(aptr + 24);
    int4 w0 = *(const int4*)(bptr);
    int4 w1 = *(const int4*)(bptr + 4);
    uint32_t sb = sptr[0];
    DqTab t = make_tab(sb);
    uint32_t d0[4], d1[4];
    dq8(pack4(w0), t, d0);
    dq8(pack4(w1), t, d1);
    u16* sAp = &sA[0][lofsA];
    *(uint4*)sAp = a0;
    *(uint4*)(sAp + 8) = a1;
    *(uint4*)(sAp + 16) = a2;
    *(uint4*)(sAp + 24) = a3;
    u16* sBp = sB[0] + lofsB;
    *(uint4*)sBp = make_uint4(d0[0], d0[1], d0[2], d0[3]);
    *(uint4*)(sBp + 8) = make_uint4(d1[0], d1[1], d1[2], d1[3]);
    obw0 = *(const int4*)(bptr + 16);
    obw1 = *(const int4*)(bptr + 20);
    obs = sptr[1];
  }

  // NSTEP = 32
#define G2_HALF(KK, P, NBI0, NBI1, NSI, NBO0, NBO1, NSO)                       \
  {                                                                            \
    __syncthreads();                                                           \
    uint4 na0, na1, na2, na3;                                                  \
    if ((KK) < 31) {                                                           \
      const u16* ap = aptr + ((KK) + 1) * 32;                                  \
      na0 = *(const uint4*)(ap);                                               \
      na1 = *(const uint4*)(ap + 8);                                           \
      na2 = *(const uint4*)(ap + 16);                                          \
      na3 = *(const uint4*)(ap + 24);                                          \
    }                                                                          \
    if ((KK) < 30) {                                                           \
      const int* bp = bptr + ((KK) + 2) * 16;                                  \
      NBO0 = *(const int4*)(bp);                                               \
      NBO1 = *(const int4*)(bp + 4);                                           \
      NSO = sptr[(KK) + 2];                                                    \
    }                                                                          \
    bf16x8 af[4], bf_[8];                                                      \
    _Pragma("unroll")                                                          \
    for (int s = 0; s < 4; ++s)                                                \
      af[s] = *(const bf16x8*)&sA[P][(w * 64 + s * 16 + c) * LDK + q * 8];     \
    _Pragma("unroll")                                                          \
    for (int t2 = 0; t2 < 8; ++t2)                                             \
      bf_[t2] = *(const bf16x8*)&sB[P][(t2 * 16 + c) * LDK + q * 8];           \
    _Pragma("unroll")                                                          \
    for (int s = 0; s < 4; ++s)                                                \
      _Pragma("unroll")                                                        \
      for (int t2 = 0; t2 < 8; ++t2)                                           \
        Cd[s][t2] = __builtin_amdgcn_mfma_f32_16x16x32_bf16(af[s], bf_[t2], Cd[s][t2], 0, 0, 0); \
    if ((KK) < 31) {                                                           \
      DqTab t = make_tab(NSI);                                                 \
      uint32_t d0[4], d1[4];                                                   \
      dq8(pack4(NBI0), t, d0);                                                 \
      dq8(pack4(NBI1), t, d1);                                                 \
      u16* sAp = &sA[(P) ^ 1][lofsA];                                          \
      *(uint4*)sAp = na0;                                                      \
      *(uint4*)(sAp + 8) = na1;                                                \
      *(uint4*)(sAp + 16) = na2;                                               \
      *(uint4*)(sAp + 24) = na3;                                               \
      u16* sBp = sB[(P) ^ 1] + lofsB;                                          \
      *(uint4*)sBp = make_uint4(d0[0], d0[1], d0[2], d0[3]);                   \
      *(uint4*)(sBp + 8) = make_uint4(d1[0], d1[1], d1[2], d1[3]);             \
    }                                                                          \
  }

  for (int kkp = 0; kkp < 16; ++kkp) {
    const int kk0 = kkp * 2;
    G2_HALF(kk0, 0, obw0, obw1, obs, ebw0, ebw1, ebs)
    G2_HALF(kk0 + 1, 1, ebw0, ebw1, ebs, obw0, obw1, obs)
  }
#undef G2_HALF

  if (pout) {
#pragma unroll
    for (int s = 0; s < 4; ++s) {
      const int mlb = w * 64 + s * 16 + q * 4;
#pragma unroll
      for (int t2 = 0; t2 < 8; ++t2) {
        const int hg = h0 + t2 * 16 + c;
#pragma unroll
        for (int r = 0; r < 4; ++r) {
          int prow = pidx_s[mlb + r];
          if (prow >= 0) pout[(size_t)prow * HD + hg] = Cd[s][t2][r];
        }
      }
    }
  } else {
#pragma unroll
    for (int s = 0; s < 4; ++s) {
      const int mlb = w * 64 + s * 16 + q * 4;
#pragma unroll
      for (int t2 = 0; t2 < 8; ++t2) {
        const int hg = h0 + t2 * 16 + c;
#pragma unroll
        for (int r = 0; r < 4; ++r) {
          int token = rows_s[mlb + r];
          if (token >= 0) atomicAdd(&out[(size_t)token * HD + hg], Cd[s][t2][r]);
        }
      }
    }
  }
}

// out[t, :] = sum over the token's 4 pairs of pout[4t+k, :]. Fully coalesced.
__global__ void finalize_kernel(const float4* __restrict__ pout, float4* __restrict__ out) {
  int j = blockIdx.x * 256 + threadIdx.x;   // T*HD/4 = 1,048,576 float4s
  int token = j >> 9;                        // HD/4 = 512 float4 per row
  int col = j & 511;
  const float4* p = pout + ((size_t)token * 4) * 512 + col;
  float4 a = p[0], b = p[512], c = p[1024], d = p[1536];
  out[j] = float4{a.x + b.x + c.x + d.x, a.y + b.y + c.y + d.y,
                  a.z + b.z + c.z + d.z, a.w + b.w + c.w + d.w};
}

extern "C" void kernel_launch(void* const* d_in, const int* in_sizes, int n_in,
                              void* d_out, int out_size, void* d_ws, size_t ws_size,
                              hipStream_t stream) {
  const float* hidden = (const float*)d_in[0];
  const float* tw = (const float*)d_in[1];
  const int* ids = (const int*)d_in[2];
  const int* gup32 = (const int*)d_in[3];        // uint8 packed bytes, uploaded as int32
  const uint32_t* gus = (const uint32_t*)d_in[4];
  const int* dwn32 = (const int*)d_in[5];
  const uint32_t* dsc = (const uint32_t*)d_in[6];
  float* out = (float*)d_out;

  char* ws = (char*)d_ws;
  int* rows = (int*)(ws);                    // 48 KB
  float* rw = (float*)(ws + 49152);          // 48 KB
  int* te = (int*)(ws + 98304);              // 192 B
  u16* xb = (u16*)(ws + 131072);             // 8 MB
  u16* act = (u16*)(ws + 8519680);           // up to 25.2 MB (MAXT*BM rows); ~21 MB written

  // Extended region (only touched if the workspace is big enough):
  const size_t POUT_OFF = 33685504ULL;       // act start + MAXT*BM*FD*2
  const size_t PIDX_OFF = POUT_OFF + (size_t)NPAIR * HD * 4;   // +67 MB
  const size_t WS_NEED = PIDX_OFF + (size_t)MAXT * BM * 4;
  const bool big = ws_size >= WS_NEED;
  float* pout = big ? (float*)(ws + POUT_OFF) : nullptr;
  int* pidx = big ? (int*)(ws + PIDX_OFF) : nullptr;

  cast_kernel<<<dim3(4096), dim3(256), 0, stream>>>(hidden, xb);
  if (!big) zero_kernel<<<dim3(4096), dim3(256), 0, stream>>>((float4*)out);
  route_kernel<<<dim3(1), dim3(256), 0, stream>>>(ids, tw, rows, rw, te, pidx);
  gemm1_kernel<<<dim3(16, MAXT), dim3(256), 0, stream>>>(xb, gup32, gus, rows, rw, te, act);
  gemm2_kernel<<<dim3(16, MAXT), dim3(256), 0, stream>>>(act, dwn32, dsc, rows, pidx, te, out, pout);
  if (big) finalize_kernel<<<dim3(1024 * 1024 / 256), dim3(256), 0, stream>>>((const float4*)pout, (float4*)out);
}

// Round 4
// 561.073 us; speedup vs baseline: 1.0437x; 1.0437x over previous
//
#include <hip/hip_runtime.h>
#include <stdint.h>

#define HD 2048
#define FD 1024
#define NE 16
#define NPAIR 8192
#define BM 256
#define MAXT 48
#define LDK 40   // 32 el + 8 pad: 80 B row stride, 16B-aligned for b128, 2-way-free banks

typedef short bf16x8 __attribute__((ext_vector_type(8)));
typedef float f32x4 __attribute__((ext_vector_type(4)));
typedef unsigned short u16;

static __device__ __forceinline__ u16 f2bf(float f) {
  uint32_t u = __float_as_uint(f);
  u += 0x7FFFu + ((u >> 16) & 1u);
  return (u16)(u >> 16);
}

// Scale-folded byte tables for e2m1 -> bf16 dequant via v_perm.
struct DqTab { uint32_t hA, hB, lA, lB; };

static __device__ __forceinline__ DqTab make_tab(uint32_t sbits) {
  int n = (int)(sbits >> 23) - 127;
  int q = n >> 1;
  uint32_t r = (uint32_t)(n & 1);
  uint32_t mq = (uint32_t)(-q);
  uint32_t sub1 = mq * 0x01010100u;  // entry 0 (zero) untouched
  uint32_t subA = mq * 0x01010101u;
  DqTab t;
  t.hA = (r ? 0x40403F00u : 0x3F3F3F00u) - sub1;
  t.hB = (r ? 0x41414040u : 0x40404040u) - subA;
  t.lA = r ? 0x40008000u : 0xC0800000u;
  t.lB = r ? 0x4000C080u : 0xC0804000u;
  return t;
}

// p: 4 packed fp4 bytes (8 values, low nibble first) -> 4 dwords of bf16 pairs
static __device__ __forceinline__ void dq8(uint32_t p, const DqTab& t, uint32_t* d) {
  uint32_t a = p & 0x0F0F0F0Fu;
  uint32_t b = (p >> 4) & 0x0F0F0F0Fu;
  uint32_t x0 = __builtin_amdgcn_perm(b, a, 0x05010400u);
  uint32_t x1 = __builtin_amdgcn_perm(b, a, 0x07030602u);
  uint32_t m0 = x0 & 0x07070707u;
  uint32_t m1 = x1 & 0x07070707u;
  uint32_t h0 = __builtin_amdgcn_perm(t.hB, t.hA, m0) | ((x0 & 0x08080808u) << 4);
  uint32_t h1 = __builtin_amdgcn_perm(t.hB, t.hA, m1) | ((x1 & 0x08080808u) << 4);
  uint32_t l0 = __builtin_amdgcn_perm(t.lB, t.lA, m0);
  uint32_t l1 = __builtin_amdgcn_perm(t.lB, t.lA, m1);
  d[0] = __builtin_amdgcn_perm(h0, l0, 0x05010400u);
  d[1] = __builtin_amdgcn_perm(h0, l0, 0x07030602u);
  d[2] = __builtin_amdgcn_perm(h1, l1, 0x05010400u);
  d[3] = __builtin_amdgcn_perm(h1, l1, 0x07030602u);
}

static __device__ __forceinline__ uint32_t pack4(int4 v) {
  return (uint32_t)(v.x & 0xFF) | ((uint32_t)(v.y & 0xFF) << 8) |
         ((uint32_t)(v.z & 0xFF) << 16) | ((uint32_t)v.w << 24);
}

// Read one 16x... one MFMA B-fragment (8 bf16) from packed LDS + staged scale.
static __device__ __forceinline__ bf16x8 dqfrag(const uint32_t* pB, const uint32_t* pS,
                                                int row, int kkloc, int q) {
  uint32_t pb = pB[row * 17 + kkloc * 4 + q];
  DqTab t = make_tab(pS[row * 4 + kkloc]);
  uint32_t d[4];
  dq8(pb, t, d);
  union { uint32_t u[4]; bf16x8 v; } cv;
  cv.u[0] = d[0]; cv.u[1] = d[1]; cv.u[2] = d[2]; cv.u[3] = d[3];
  return cv.v;
}

__global__ void cast_kernel(const float* __restrict__ x, u16* __restrict__ xb) {
  int i = blockIdx.x * 256 + threadIdx.x;
  float4 v = ((const float4*)x)[i];
  ushort4 o;
  o.x = f2bf(v.x); o.y = f2bf(v.y); o.z = f2bf(v.z); o.w = f2bf(v.w);
  ((ushort4*)xb)[i] = o;
}

__global__ void zero_kernel(float4* __restrict__ out) {
  out[blockIdx.x * 256 + threadIdx.x] = float4{0.f, 0.f, 0.f, 0.f};
}

__global__ void route_kernel(const int* __restrict__ ids, const float* __restrict__ tw,
                             int* __restrict__ rows, float* __restrict__ rw,
                             int* __restrict__ te, int* __restrict__ pidx) {
  __shared__ int cnt[NE], base[NE], run[NE];
  int tid = threadIdx.x;
  if (tid < NE) { cnt[tid] = 0; run[tid] = 0; }
  __syncthreads();
  for (int i = tid; i < NPAIR; i += 256) atomicAdd(&cnt[ids[i]], 1);
  __syncthreads();
  if (tid == 0) {
    int cum = 0;
    for (int e = 0; e < NE; ++e) {
      base[e] = cum;
      int nt = (cnt[e] + BM - 1) >> 8;
      for (int j = 0; j < nt; ++j) te[(cum >> 8) + j] = e;
      cum += nt << 8;
    }
    for (int t = cum >> 8; t < MAXT; ++t) te[t] = -1;
  }
  __syncthreads();
  for (int i = tid; i < MAXT * BM; i += 256) {
    rows[i] = -1;
    rw[i] = 0.f;
    if (pidx) pidx[i] = -1;
  }
  __syncthreads();
  for (int i = tid; i < NPAIR; i += 256) {
    int e = ids[i];
    int p = base[e] + atomicAdd(&run[e], 1);
    rows[p] = i >> 2;
    rw[p] = tw[i];
    if (pidx) pidx[p] = i;
  }
}

// gate_up GEMM + SwiGLU + routing weight -> act (bf16). BM=256, BN=64+64, BK=32.
// B fetched in 256B-contiguous (inflated) runs per row at 4-K-step stage granularity,
// staged PACKED in LDS (+ scales), dequantized on read. A staged bf16 per K-step (dbuf).
// ONE barrier per K-step; 32 MFMA per barrier per wave.
__global__ __launch_bounds__(256, 2) void gemm1_kernel(
    const u16* __restrict__ xb, const int* __restrict__ gup32,
    const uint32_t* __restrict__ gus, const int* __restrict__ rows,
    const float* __restrict__ rw, const int* __restrict__ te,
    u16* __restrict__ act) {
  const int tile = blockIdx.y;
  const int e = te[tile];
  if (e < 0) return;
  const int f0 = blockIdx.x * 64;

  __shared__ u16 sA[2][BM * LDK];        // 40 KB
  __shared__ uint32_t sBp[2][128 * 17];  // 17 KB packed fp4, 68B row stride
  __shared__ uint32_t sSc[2][128 * 4];   // 4 KB scales
  __shared__ int rows_s[BM];
  __shared__ float rw_s[BM];

  const int tid = threadIdx.x;
  rows_s[tid] = rows[tile * BM + tid];
  rw_s[tid] = rw[tile * BM + tid];
  __syncthreads();

  int arow = rows_s[tid];
  arow = arow < 0 ? 0 : arow;
  const u16* aptr = xb + (size_t)arow * HD;
  const int lofsA = tid * LDK;

  // B staging thread map: 16 lanes cover one row's 256B inflated stage-window.
  const int srow = tid >> 4;   // 0..15 (+16 per pass)
  const int sseg = tid & 15;   // 16B chunk within the 256B window
  const int* gb = gup32 + (size_t)(e * 2048 + f0 + srow) * 1024 + sseg * 4;
  // scale staging: 2 u32 per thread per stage
  const int trow = tid >> 1;   // 0..127
  const int tpair = (tid & 1) * 2;
  const int to = trow < 64 ? f0 + trow : 1024 + f0 + (trow - 64);
  const uint32_t* scb = gus + (size_t)(e * 2048 + to) * 64 + tpair;

  const int lane = tid & 63;
  const int w = tid >> 6;
  const int q = lane >> 4, c = lane & 15;

  f32x4 Cg[4][4], Cu[4][4];
#pragma unroll
  for (int s = 0; s < 4; ++s)
#pragma unroll
    for (int t2 = 0; t2 < 4; ++t2) {
      Cg[s][t2] = f32x4{0.f, 0.f, 0.f, 0.f};
      Cu[s][t2] = f32x4{0.f, 0.f, 0.f, 0.f};
    }

  int4 breg[8];
  uint2 sreg;

  // prologue: B stage 0 + scales, A K-step 0
  {
#pragma unroll
    for (int pp = 0; pp < 8; ++pp)
      breg[pp] = *(const int4*)(gb + (pp < 4 ? 0 : 983040) + pp * 16384);
    sreg = *(const uint2*)scb;
    uint4 a0 = *(const uint4*)(aptr);
    uint4 a1 = *(const uint4*)(aptr + 8);
    uint4 a2 = *(const uint4*)(aptr + 16);
    uint4 a3 = *(const uint4*)(aptr + 24);
#pragma unroll
    for (int pp = 0; pp < 8; ++pp)
      sBp[0][(srow + pp * 16) * 17 + sseg] = pack4(breg[pp]);
    sSc[0][trow * 4 + tpair] = sreg.x;
    sSc[0][trow * 4 + tpair + 1] = sreg.y;
    u16* sAp = &sA[0][lofsA];
    *(uint4*)sAp = a0;
    *(uint4*)(sAp + 8) = a1;
    *(uint4*)(sAp + 16) = a2;
    *(uint4*)(sAp + 24) = a3;
  }

  for (int kk = 0; kk < 64; ++kk) {
    const int p = kk & 1;
    const int sb = (kk >> 2) & 1;
    const int kkloc = kk & 3;
    __syncthreads();

    // A prefetch next K-step
    uint4 na0, na1, na2, na3;
    if (kk < 63) {
      const u16* ap = aptr + (kk + 1) * 32;
      na0 = *(const uint4*)(ap);
      na1 = *(const uint4*)(ap + 8);
      na2 = *(const uint4*)(ap + 16);
      na3 = *(const uint4*)(ap + 24);
    }
    // B next-stage prefetch (256B contiguous per row), issued at stage head
    if (kkloc == 0 && kk + 4 < 64) {
      const int boff = ((kk >> 2) + 1) * 64;
#pragma unroll
      for (int pp = 0; pp < 8; ++pp)
        breg[pp] = *(const int4*)(gb + boff + (pp < 4 ? 0 : 983040) + pp * 16384);
      sreg = *(const uint2*)(scb + ((kk >> 2) + 1) * 4);
    }

    bf16x8 af[4];
#pragma unroll
    for (int s = 0; s < 4; ++s)
      af[s] = *(const bf16x8*)&sA[p][(w * 64 + s * 16 + c) * LDK + q * 8];

#pragma unroll
    for (int t2 = 0; t2 < 4; ++t2) {
      bf16x8 bg = dqfrag(sBp[sb], sSc[sb], t2 * 16 + c, kkloc, q);
      bf16x8 bu = dqfrag(sBp[sb], sSc[sb], 64 + t2 * 16 + c, kkloc, q);
#pragma unroll
      for (int s = 0; s < 4; ++s) {
        Cg[s][t2] = __builtin_amdgcn_mfma_f32_16x16x32_bf16(af[s], bg, Cg[s][t2], 0, 0, 0);
        Cu[s][t2] = __builtin_amdgcn_mfma_f32_16x16x32_bf16(af[s], bu, Cu[s][t2], 0, 0, 0);
      }
    }

    if (kk < 63) {
      u16* sAp = &sA[p ^ 1][lofsA];
      *(uint4*)sAp = na0;
      *(uint4*)(sAp + 8) = na1;
      *(uint4*)(sAp + 16) = na2;
      *(uint4*)(sAp + 24) = na3;
    }
    if (kkloc == 3 && kk < 63) {
      const int sbn = sb ^ 1;
#pragma unroll
      for (int pp = 0; pp < 8; ++pp)
        sBp[sbn][(srow + pp * 16) * 17 + sseg] = pack4(breg[pp]);
      sSc[sbn][trow * 4 + tpair] = sreg.x;
      sSc[sbn][trow * 4 + tpair + 1] = sreg.y;
    }
  }

#pragma unroll
  for (int s = 0; s < 4; ++s) {
    const int mlb = w * 64 + s * 16 + q * 4;
#pragma unroll
    for (int t2 = 0; t2 < 4; ++t2) {
      const int fg = f0 + t2 * 16 + c;
#pragma unroll
      for (int r = 0; r < 4; ++r) {
        const int ml = mlb + r;
        float g = Cg[s][t2][r];
        float u = Cu[s][t2][r];
        float aval = g / (1.f + __expf(-g)) * u * rw_s[ml];
        act[(size_t)(tile * BM + ml) * FD + fg] = f2bf(aval);
      }
    }
  }
}

// down GEMM. BM=256, BN=128, BK=32. Same staging scheme as gemm1.
// Epilogue: if pout != null, non-overlapping f32 partials (no atomics); else atomicAdd.
__global__ __launch_bounds__(256, 2) void gemm2_kernel(
    const u16* __restrict__ act, const int* __restrict__ dwn32,
    const uint32_t* __restrict__ dsc, const int* __restrict__ rows,
    const int* __restrict__ pidx, const int* __restrict__ te,
    float* __restrict__ out, float* __restrict__ pout) {
  const int tile = blockIdx.y;
  const int e = te[tile];
  if (e < 0) return;
  const int h0 = blockIdx.x * 128;

  __shared__ u16 sA[2][BM * LDK];        // 40 KB
  __shared__ uint32_t sBp[2][128 * 17];  // 17 KB
  __shared__ uint32_t sSc[2][128 * 4];   // 4 KB
  __shared__ int rows_s[BM];
  __shared__ int pidx_s[BM];

  const int tid = threadIdx.x;
  rows_s[tid] = rows[tile * BM + tid];
  pidx_s[tid] = pout ? pidx[tile * BM + tid] : -1;
  __syncthreads();

  const u16* aptr = act + (size_t)(tile * BM + tid) * FD;
  const int lofsA = tid * LDK;

  const int srow = tid >> 4;
  const int sseg = tid & 15;
  const int* gb = dwn32 + (size_t)(e * 2048 + h0 + srow) * 512 + sseg * 4;
  const int trow = tid >> 1;
  const int tpair = (tid & 1) * 2;
  const uint32_t* scb = dsc + (size_t)(e * 2048 + h0 + trow) * 32 + tpair;

  const int lane = tid & 63;
  const int w = tid >> 6;
  const int q = lane >> 4, c = lane & 15;

  f32x4 Cd[4][8];
#pragma unroll
  for (int s = 0; s < 4; ++s)
#pragma unroll
    for (int t2 = 0; t2 < 8; ++t2) Cd[s][t2] = f32x4{0.f, 0.f, 0.f, 0.f};

  int4 breg[8];
  uint2 sreg;

  {
#pragma unroll
    for (int pp = 0; pp < 8; ++pp)
      breg[pp] = *(const int4*)(gb + pp * 8192);
    sreg = *(const uint2*)scb;
    uint4 a0 = *(const uint4*)(aptr);
    uint4 a1 = *(const uint4*)(aptr + 8);
    uint4 a2 = *(const uint4*)(aptr + 16);
    uint4 a3 = *(const uint4*)(aptr + 24);
#pragma unroll
    for (int pp = 0; pp < 8; ++pp)
      sBp[0][(srow + pp * 16) * 17 + sseg] = pack4(breg[pp]);
    sSc[0][trow * 4 + tpair] = sreg.x;
    sSc[0][trow * 4 + tpair + 1] = sreg.y;
    u16* sAp = &sA[0][lofsA];
    *(uint4*)sAp = a0;
    *(uint4*)(sAp + 8) = a1;
    *(uint4*)(sAp + 16) = a2;
    *(uint4*)(sAp + 24) = a3;
  }

  for (int kk = 0; kk < 32; ++kk) {
    const int p = kk & 1;
    const int sb = (kk >> 2) & 1;
    const int kkloc = kk & 3;
    __syncthreads();

    uint4 na0, na1, na2, na3;
    if (kk < 31) {
      const u16* ap = aptr + (kk + 1) * 32;
      na0 = *(const uint4*)(ap);
      na1 = *(const uint4*)(ap + 8);
      na2 = *(const uint4*)(ap + 16);
      na3 = *(const uint4*)(ap + 24);
    }
    if (kkloc == 0 && kk + 4 < 32) {
      const int boff = ((kk >> 2) + 1) * 64;
#pragma unroll
      for (int pp = 0; pp < 8; ++pp)
        breg[pp] = *(const int4*)(gb + boff + pp * 8192);
      sreg = *(const uint2*)(scb + ((kk >> 2) + 1) * 4);
    }

    bf16x8 af[4];
#pragma unroll
    for (int s = 0; s < 4; ++s)
      af[s] = *(const bf16x8*)&sA[p][(w * 64 + s * 16 + c) * LDK + q * 8];

#pragma unroll
    for (int t2 = 0; t2 < 8; ++t2) {
      bf16x8 bf_ = dqfrag(sBp[sb], sSc[sb], t2 * 16 + c, kkloc, q);
#pragma unroll
      for (int s = 0; s < 4; ++s)
        Cd[s][t2] = __builtin_amdgcn_mfma_f32_16x16x32_bf16(af[s], bf_, Cd[s][t2], 0, 0, 0);
    }

    if (kk < 31) {
      u16* sAp = &sA[p ^ 1][lofsA];
      *(uint4*)sAp = na0;
      *(uint4*)(sAp + 8) = na1;
      *(uint4*)(sAp + 16) = na2;
      *(uint4*)(sAp + 24) = na3;
    }
    if (kkloc == 3 && kk < 31) {
      const int sbn = sb ^ 1;
#pragma unroll
      for (int pp = 0; pp < 8; ++pp)
        sBp[sbn][(srow + pp * 16) * 17 + sseg] = pack4(breg[pp]);
      sSc[sbn][trow * 4 + tpair] = sreg.x;
      sSc[sbn][trow * 4 + tpair + 1] = sreg.y;
    }
  }

  if (pout) {
#pragma unroll
    for (int s = 0; s < 4; ++s) {
      const int mlb = w * 64 + s * 16 + q * 4;
#pragma unroll
      for (int t2 = 0; t2 < 8; ++t2) {
        const int hg = h0 + t2 * 16 + c;
#pragma unroll
        for (int r = 0; r < 4; ++r) {
          int prow = pidx_s[mlb + r];
          if (prow >= 0) pout[(size_t)prow * HD + hg] = Cd[s][t2][r];
        }
      }
    }
  } else {
#pragma unroll
    for (int s = 0; s < 4; ++s) {
      const int mlb = w * 64 + s * 16 + q * 4;
#pragma unroll
      for (int t2 = 0; t2 < 8; ++t2) {
        const int hg = h0 + t2 * 16 + c;
#pragma unroll
        for (int r = 0; r < 4; ++r) {
          int token = rows_s[mlb + r];
          if (token >= 0) atomicAdd(&out[(size_t)token * HD + hg], Cd[s][t2][r]);
        }
      }
    }
  }
}

// out[t, :] = sum over the token's 4 pairs of pout[4t+k, :]. Fully coalesced.
__global__ void finalize_kernel(const float4* __restrict__ pout, float4* __restrict__ out) {
  int j = blockIdx.x * 256 + threadIdx.x;   // T*HD/4 = 1,048,576 float4s
  int token = j >> 9;                        // HD/4 = 512 float4 per row
  int col = j & 511;
  const float4* p = pout + ((size_t)token * 4) * 512 + col;
  float4 a = p[0], b = p[512], c = p[1024], d = p[1536];
  out[j] = float4{a.x + b.x + c.x + d.x, a.y + b.y + c.y + d.y,
                  a.z + b.z + c.z + d.z, a.w + b.w + c.w + d.w};
}

extern "C" void kernel_launch(void* const* d_in, const int* in_sizes, int n_in,
                              void* d_out, int out_size, void* d_ws, size_t ws_size,
                              hipStream_t stream) {
  const float* hidden = (const float*)d_in[0];
  const float* tw = (const float*)d_in[1];
  const int* ids = (const int*)d_in[2];
  const int* gup32 = (const int*)d_in[3];        // uint8 packed bytes, uploaded as int32
  const uint32_t* gus = (const uint32_t*)d_in[4];
  const int* dwn32 = (const int*)d_in[5];
  const uint32_t* dsc = (const uint32_t*)d_in[6];
  float* out = (float*)d_out;

  char* ws = (char*)d_ws;
  int* rows = (int*)(ws);                    // 48 KB
  float* rw = (float*)(ws + 49152);          // 48 KB
  int* te = (int*)(ws + 98304);              // 192 B
  u16* xb = (u16*)(ws + 131072);             // 8 MB
  u16* act = (u16*)(ws + 8519680);           // up to 25.2 MB (MAXT*BM rows); ~21 MB written

  // Extended region (only touched if the workspace is big enough):
  const size_t POUT_OFF = 33685504ULL;       // act start + MAXT*BM*FD*2
  const size_t PIDX_OFF = POUT_OFF + (size_t)NPAIR * HD * 4;   // +67 MB
  const size_t WS_NEED = PIDX_OFF + (size_t)MAXT * BM * 4;
  const bool big = ws_size >= WS_NEED;
  float* pout = big ? (float*)(ws + POUT_OFF) : nullptr;
  int* pidx = big ? (int*)(ws + PIDX_OFF) : nullptr;

  cast_kernel<<<dim3(4096), dim3(256), 0, stream>>>(hidden, xb);
  if (!big) zero_kernel<<<dim3(4096), dim3(256), 0, stream>>>((float4*)out);
  route_kernel<<<dim3(1), dim3(256), 0, stream>>>(ids, tw, rows, rw, te, pidx);
  gemm1_kernel<<<dim3(16, MAXT), dim3(256), 0, stream>>>(xb, gup32, gus, rows, rw, te, act);
  gemm2_kernel<<<dim3(16, MAXT), dim3(256), 0, stream>>>(act, dwn32, dsc, rows, pidx, te, out, pout);
  if (big) finalize_kernel<<<dim3(1024 * 1024 / 256), dim3(256), 0, stream>>>((const float4*)pout, (float4*)out);
}

// Round 5
// 541.331 us; speedup vs baseline: 1.0817x; 1.0365x over previous
//
#include <hip/hip_runtime.h>
#include <stdint.h>

#define HD 2048
#define FD 1024
#define NE 16
#define NPAIR 8192
#define BM 256
#define MAXT 48
#define LDK 40   // 32 el + 8 pad: 80 B row stride, 16B-aligned for b128

typedef short bf16x8 __attribute__((ext_vector_type(8)));
typedef float f32x4 __attribute__((ext_vector_type(4)));
typedef unsigned short u16;

static __device__ __forceinline__ u16 f2bf(float f) {
  uint32_t u = __float_as_uint(f);
  u += 0x7FFFu + ((u >> 16) & 1u);
  return (u16)(u >> 16);
}

// Scale-folded byte tables for e2m1 -> bf16 dequant via v_perm.
struct DqTab { uint32_t hA, hB, lA, lB; };

static __device__ __forceinline__ DqTab make_tab(uint32_t sbits) {
  int n = (int)(sbits >> 23) - 127;
  int q = n >> 1;
  uint32_t r = (uint32_t)(n & 1);
  uint32_t mq = (uint32_t)(-q);
  uint32_t sub1 = mq * 0x01010100u;  // entry 0 (zero) untouched
  uint32_t subA = mq * 0x01010101u;
  DqTab t;
  t.hA = (r ? 0x40403F00u : 0x3F3F3F00u) - sub1;
  t.hB = (r ? 0x41414040u : 0x40404040u) - subA;
  t.lA = r ? 0x40008000u : 0xC0800000u;
  t.lB = r ? 0x4000C080u : 0xC0804000u;
  return t;
}

// p: 4 packed fp4 bytes (8 values, low nibble first) -> 4 dwords of bf16 pairs
static __device__ __forceinline__ void dq8(uint32_t p, const DqTab& t, uint32_t* d) {
  uint32_t a = p & 0x0F0F0F0Fu;
  uint32_t b = (p >> 4) & 0x0F0F0F0Fu;
  uint32_t x0 = __builtin_amdgcn_perm(b, a, 0x05010400u);
  uint32_t x1 = __builtin_amdgcn_perm(b, a, 0x07030602u);
  uint32_t m0 = x0 & 0x07070707u;
  uint32_t m1 = x1 & 0x07070707u;
  uint32_t h0 = __builtin_amdgcn_perm(t.hB, t.hA, m0) | ((x0 & 0x08080808u) << 4);
  uint32_t h1 = __builtin_amdgcn_perm(t.hB, t.hA, m1) | ((x1 & 0x08080808u) << 4);
  uint32_t l0 = __builtin_amdgcn_perm(t.lB, t.lA, m0);
  uint32_t l1 = __builtin_amdgcn_perm(t.lB, t.lA, m1);
  d[0] = __builtin_amdgcn_perm(h0, l0, 0x05010400u);
  d[1] = __builtin_amdgcn_perm(h0, l0, 0x07030602u);
  d[2] = __builtin_amdgcn_perm(h1, l1, 0x05010400u);
  d[3] = __builtin_amdgcn_perm(h1, l1, 0x07030602u);
}

static __device__ __forceinline__ uint32_t pack4(int4 v) {
  return (uint32_t)(v.x & 0xFF) | ((uint32_t)(v.y & 0xFF) << 8) |
         ((uint32_t)(v.z & 0xFF) << 16) | ((uint32_t)v.w << 24);
}

// Read one MFMA B-fragment (8 bf16) from packed LDS + staged scale.
static __device__ __forceinline__ bf16x8 dqfrag(const uint32_t* pB, const uint32_t* pS,
                                                int row, int kkloc, int q) {
  uint32_t pb = pB[row * 17 + kkloc * 4 + q];
  DqTab t = make_tab(pS[row * 4 + kkloc]);
  uint32_t d[4];
  dq8(pb, t, d);
  union { uint32_t u[4]; bf16x8 v; } cv;
  cv.u[0] = d[0]; cv.u[1] = d[1]; cv.u[2] = d[2]; cv.u[3] = d[3];
  return cv.v;
}

__global__ void cast_kernel(const float* __restrict__ x, u16* __restrict__ xb) {
  int i = blockIdx.x * 256 + threadIdx.x;
  float4 v = ((const float4*)x)[i];
  ushort4 o;
  o.x = f2bf(v.x); o.y = f2bf(v.y); o.z = f2bf(v.z); o.w = f2bf(v.w);
  ((ushort4*)xb)[i] = o;
}

__global__ void zero_kernel(float4* __restrict__ out) {
  out[blockIdx.x * 256 + threadIdx.x] = float4{0.f, 0.f, 0.f, 0.f};
}

__global__ void route_kernel(const int* __restrict__ ids, const float* __restrict__ tw,
                             int* __restrict__ rows, float* __restrict__ rw,
                             int* __restrict__ te, int* __restrict__ pidx) {
  __shared__ int cnt[NE], base[NE], run[NE];
  int tid = threadIdx.x;
  if (tid < NE) { cnt[tid] = 0; run[tid] = 0; }
  __syncthreads();
  for (int i = tid; i < NPAIR; i += 256) atomicAdd(&cnt[ids[i]], 1);
  __syncthreads();
  if (tid == 0) {
    int cum = 0;
    for (int e = 0; e < NE; ++e) {
      base[e] = cum;
      int nt = (cnt[e] + BM - 1) >> 8;
      for (int j = 0; j < nt; ++j) te[(cum >> 8) + j] = e;
      cum += nt << 8;
    }
    for (int t = cum >> 8; t < MAXT; ++t) te[t] = -1;
  }
  __syncthreads();
  for (int i = tid; i < MAXT * BM; i += 256) {
    rows[i] = -1;
    rw[i] = 0.f;
    if (pidx) pidx[i] = -1;
  }
  __syncthreads();
  for (int i = tid; i < NPAIR; i += 256) {
    int e = ids[i];
    int p = base[e] + atomicAdd(&run[e], 1);
    rows[p] = i >> 2;
    rw[p] = tw[i];
    if (pidx) pidx[p] = i;
  }
}

// gate_up GEMM + SwiGLU + routing weight -> act (bf16). BM=256, BN=64+64, BK=32.
// A staging COALESCED: each wave instr covers 16 rows x 64B full lines
// (thread handles 4 rows, 16B seg each) instead of 64 rows x 16B.
// B: 256B-contiguous runs per row, 4-K-step stage granularity, packed LDS,
// dequant on read. ONE barrier per K-step.
__global__ __launch_bounds__(256, 2) void gemm1_kernel(
    const u16* __restrict__ xb, const int* __restrict__ gup32,
    const uint32_t* __restrict__ gus, const int* __restrict__ rows,
    const float* __restrict__ rw, const int* __restrict__ te,
    u16* __restrict__ act) {
  const int tile = blockIdx.y;
  const int e = te[tile];
  if (e < 0) return;
  const int f0 = blockIdx.x * 64;

  __shared__ u16 sA[2][BM * LDK];        // 40 KB
  __shared__ uint32_t sBp[2][128 * 17];  // 17 KB packed fp4, 68B row stride
  __shared__ uint32_t sSc[2][128 * 4];   // 4 KB scales
  __shared__ int rows_s[BM];
  __shared__ float rw_s[BM];

  const int tid = threadIdx.x;
  rows_s[tid] = rows[tile * BM + tid];
  rw_s[tid] = rw[tile * BM + tid];
  __syncthreads();

  // A staging map: thread -> 4 rows ((tid>>2)+r*64), 16B segment (tid&3) of each
  // row's 64B K-slice. Per instr: 16 rows x 64B coalesced lines.
  const int sr4 = tid >> 2, sg4 = tid & 3;
  uint32_t aof[4];
  int lofsAr[4];
#pragma unroll
  for (int r = 0; r < 4; ++r) {
    int rr = rows_s[sr4 + r * 64];
    rr = rr < 0 ? 0 : rr;
    aof[r] = (uint32_t)rr * HD + sg4 * 8;
    lofsAr[r] = (sr4 + r * 64) * LDK + sg4 * 8;
  }

  // B staging thread map: 16 lanes cover one row's 256B inflated stage-window.
  const int srow = tid >> 4;   // 0..15 (+16 per pass)
  const int sseg = tid & 15;   // 16B chunk within the 256B window
  const int* gb = gup32 + (size_t)(e * 2048 + f0 + srow) * 1024 + sseg * 4;
  // scale staging: 2 u32 per thread per stage
  const int trow = tid >> 1;   // 0..127
  const int tpair = (tid & 1) * 2;
  const int to = trow < 64 ? f0 + trow : 1024 + f0 + (trow - 64);
  const uint32_t* scb = gus + (size_t)(e * 2048 + to) * 64 + tpair;

  const int lane = tid & 63;
  const int w = tid >> 6;
  const int q = lane >> 4, c = lane & 15;

  f32x4 Cg[4][4], Cu[4][4];
#pragma unroll
  for (int s = 0; s < 4; ++s)
#pragma unroll
    for (int t2 = 0; t2 < 4; ++t2) {
      Cg[s][t2] = f32x4{0.f, 0.f, 0.f, 0.f};
      Cu[s][t2] = f32x4{0.f, 0.f, 0.f, 0.f};
    }

  int4 breg[8];
  uint2 sreg;

  // prologue: B stage 0 + scales, A K-step 0
  {
#pragma unroll
    for (int pp = 0; pp < 8; ++pp)
      breg[pp] = *(const int4*)(gb + (pp < 4 ? 0 : 983040) + pp * 16384);
    sreg = *(const uint2*)scb;
    uint4 a[4];
#pragma unroll
    for (int r = 0; r < 4; ++r) a[r] = *(const uint4*)(xb + aof[r]);
#pragma unroll
    for (int pp = 0; pp < 8; ++pp)
      sBp[0][(srow + pp * 16) * 17 + sseg] = pack4(breg[pp]);
    sSc[0][trow * 4 + tpair] = sreg.x;
    sSc[0][trow * 4 + tpair + 1] = sreg.y;
#pragma unroll
    for (int r = 0; r < 4; ++r) *(uint4*)&sA[0][lofsAr[r]] = a[r];
  }

  for (int kk = 0; kk < 64; ++kk) {
    const int p = kk & 1;
    const int sb = (kk >> 2) & 1;
    const int kkloc = kk & 3;
    __syncthreads();

    // A prefetch next K-step (coalesced 16-row lines)
    uint4 na[4];
    if (kk < 63) {
#pragma unroll
      for (int r = 0; r < 4; ++r)
        na[r] = *(const uint4*)(xb + aof[r] + (kk + 1) * 32);
    }
    // B next-stage prefetch (256B contiguous per row), issued at stage head
    if (kkloc == 0 && kk + 4 < 64) {
      const int boff = ((kk >> 2) + 1) * 64;
#pragma unroll
      for (int pp = 0; pp < 8; ++pp)
        breg[pp] = *(const int4*)(gb + boff + (pp < 4 ? 0 : 983040) + pp * 16384);
      sreg = *(const uint2*)(scb + ((kk >> 2) + 1) * 4);
    }

    bf16x8 af[4];
#pragma unroll
    for (int s = 0; s < 4; ++s)
      af[s] = *(const bf16x8*)&sA[p][(w * 64 + s * 16 + c) * LDK + q * 8];

#pragma unroll
    for (int t2 = 0; t2 < 4; ++t2) {
      bf16x8 bg = dqfrag(sBp[sb], sSc[sb], t2 * 16 + c, kkloc, q);
      bf16x8 bu = dqfrag(sBp[sb], sSc[sb], 64 + t2 * 16 + c, kkloc, q);
#pragma unroll
      for (int s = 0; s < 4; ++s) {
        Cg[s][t2] = __builtin_amdgcn_mfma_f32_16x16x32_bf16(af[s], bg, Cg[s][t2], 0, 0, 0);
        Cu[s][t2] = __builtin_amdgcn_mfma_f32_16x16x32_bf16(af[s], bu, Cu[s][t2], 0, 0, 0);
      }
    }

    if (kk < 63) {
#pragma unroll
      for (int r = 0; r < 4; ++r) *(uint4*)&sA[p ^ 1][lofsAr[r]] = na[r];
    }
    if (kkloc == 3 && kk < 63) {
      const int sbn = sb ^ 1;
#pragma unroll
      for (int pp = 0; pp < 8; ++pp)
        sBp[sbn][(srow + pp * 16) * 17 + sseg] = pack4(breg[pp]);
      sSc[sbn][trow * 4 + tpair] = sreg.x;
      sSc[sbn][trow * 4 + tpair + 1] = sreg.y;
    }
  }

#pragma unroll
  for (int s = 0; s < 4; ++s) {
    const int mlb = w * 64 + s * 16 + q * 4;
#pragma unroll
    for (int t2 = 0; t2 < 4; ++t2) {
      const int fg = f0 + t2 * 16 + c;
#pragma unroll
      for (int r = 0; r < 4; ++r) {
        const int ml = mlb + r;
        float g = Cg[s][t2][r];
        float u = Cu[s][t2][r];
        float aval = g / (1.f + __expf(-g)) * u * rw_s[ml];
        act[(size_t)(tile * BM + ml) * FD + fg] = f2bf(aval);
      }
    }
  }
}

// down GEMM. BM=256, BN=128, BK=32. Same A/B staging scheme as gemm1.
// Epilogue: if pout != null, non-overlapping f32 partials (no atomics); else atomicAdd.
__global__ __launch_bounds__(256, 2) void gemm2_kernel(
    const u16* __restrict__ act, const int* __restrict__ dwn32,
    const uint32_t* __restrict__ dsc, const int* __restrict__ rows,
    const int* __restrict__ pidx, const int* __restrict__ te,
    float* __restrict__ out, float* __restrict__ pout) {
  const int tile = blockIdx.y;
  const int e = te[tile];
  if (e < 0) return;
  const int h0 = blockIdx.x * 128;

  __shared__ u16 sA[2][BM * LDK];        // 40 KB
  __shared__ uint32_t sBp[2][128 * 17];  // 17 KB
  __shared__ uint32_t sSc[2][128 * 4];   // 4 KB
  __shared__ int rows_s[BM];
  __shared__ int pidx_s[BM];

  const int tid = threadIdx.x;
  rows_s[tid] = rows[tile * BM + tid];
  pidx_s[tid] = pout ? pidx[tile * BM + tid] : -1;
  __syncthreads();

  // A staging map: coalesced 16-row x 64B lines (act rows are contiguous in tile).
  const int sr4 = tid >> 2, sg4 = tid & 3;
  uint32_t aof[4];
  int lofsAr[4];
#pragma unroll
  for (int r = 0; r < 4; ++r) {
    aof[r] = (uint32_t)(tile * BM + sr4 + r * 64) * FD + sg4 * 8;
    lofsAr[r] = (sr4 + r * 64) * LDK + sg4 * 8;
  }

  const int srow = tid >> 4;
  const int sseg = tid & 15;
  const int* gb = dwn32 + (size_t)(e * 2048 + h0 + srow) * 512 + sseg * 4;
  const int trow = tid >> 1;
  const int tpair = (tid & 1) * 2;
  const uint32_t* scb = dsc + (size_t)(e * 2048 + h0 + trow) * 32 + tpair;

  const int lane = tid & 63;
  const int w = tid >> 6;
  const int q = lane >> 4, c = lane & 15;

  f32x4 Cd[4][8];
#pragma unroll
  for (int s = 0; s < 4; ++s)
#pragma unroll
    for (int t2 = 0; t2 < 8; ++t2) Cd[s][t2] = f32x4{0.f, 0.f, 0.f, 0.f};

  int4 breg[8];
  uint2 sreg;

  {
#pragma unroll
    for (int pp = 0; pp < 8; ++pp)
      breg[pp] = *(const int4*)(gb + pp * 8192);
    sreg = *(const uint2*)scb;
    uint4 a[4];
#pragma unroll
    for (int r = 0; r < 4; ++r) a[r] = *(const uint4*)(act + aof[r]);
#pragma unroll
    for (int pp = 0; pp < 8; ++pp)
      sBp[0][(srow + pp * 16) * 17 + sseg] = pack4(breg[pp]);
    sSc[0][trow * 4 + tpair] = sreg.x;
    sSc[0][trow * 4 + tpair + 1] = sreg.y;
#pragma unroll
    for (int r = 0; r < 4; ++r) *(uint4*)&sA[0][lofsAr[r]] = a[r];
  }

  for (int kk = 0; kk < 32; ++kk) {
    const int p = kk & 1;
    const int sb = (kk >> 2) & 1;
    const int kkloc = kk & 3;
    __syncthreads();

    uint4 na[4];
    if (kk < 31) {
#pragma unroll
      for (int r = 0; r < 4; ++r)
        na[r] = *(const uint4*)(act + aof[r] + (kk + 1) * 32);
    }
    if (kkloc == 0 && kk + 4 < 32) {
      const int boff = ((kk >> 2) + 1) * 64;
#pragma unroll
      for (int pp = 0; pp < 8; ++pp)
        breg[pp] = *(const int4*)(gb + boff + pp * 8192);
      sreg = *(const uint2*)(scb + ((kk >> 2) + 1) * 4);
    }

    bf16x8 af[4];
#pragma unroll
    for (int s = 0; s < 4; ++s)
      af[s] = *(const bf16x8*)&sA[p][(w * 64 + s * 16 + c) * LDK + q * 8];

#pragma unroll
    for (int t2 = 0; t2 < 8; ++t2) {
      bf16x8 bf_ = dqfrag(sBp[sb], sSc[sb], t2 * 16 + c, kkloc, q);
#pragma unroll
      for (int s = 0; s < 4; ++s)
        Cd[s][t2] = __builtin_amdgcn_mfma_f32_16x16x32_bf16(af[s], bf_, Cd[s][t2], 0, 0, 0);
    }

    if (kk < 31) {
#pragma unroll
      for (int r = 0; r < 4; ++r) *(uint4*)&sA[p ^ 1][lofsAr[r]] = na[r];
    }
    if (kkloc == 3 && kk < 31) {
      const int sbn = sb ^ 1;
#pragma unroll
      for (int pp = 0; pp < 8; ++pp)
        sBp[sbn][(srow + pp * 16) * 17 + sseg] = pack4(breg[pp]);
      sSc[sbn][trow * 4 + tpair] = sreg.x;
      sSc[sbn][trow * 4 + tpair + 1] = sreg.y;
    }
  }

  if (pout) {
#pragma unroll
    for (int s = 0; s < 4; ++s) {
      const int mlb = w * 64 + s * 16 + q * 4;
#pragma unroll
      for (int t2 = 0; t2 < 8; ++t2) {
        const int hg = h0 + t2 * 16 + c;
#pragma unroll
        for (int r = 0; r < 4; ++r) {
          int prow = pidx_s[mlb + r];
          if (prow >= 0) pout[(size_t)prow * HD + hg] = Cd[s][t2][r];
        }
      }
    }
  } else {
#pragma unroll
    for (int s = 0; s < 4; ++s) {
      const int mlb = w * 64 + s * 16 + q * 4;
#pragma unroll
      for (int t2 = 0; t2 < 8; ++t2) {
        const int hg = h0 + t2 * 16 + c;
#pragma unroll
        for (int r = 0; r < 4; ++r) {
          int token = rows_s[mlb + r];
          if (token >= 0) atomicAdd(&out[(size_t)token * HD + hg], Cd[s][t2][r]);
        }
      }
    }
  }
}

// out[t, :] = sum over the token's 4 pairs of pout[4t+k, :]. Fully coalesced.
__global__ void finalize_kernel(const float4* __restrict__ pout, float4* __restrict__ out) {
  int j = blockIdx.x * 256 + threadIdx.x;   // T*HD/4 = 1,048,576 float4s
  int token = j >> 9;                        // HD/4 = 512 float4 per row
  int col = j & 511;
  const float4* p = pout + ((size_t)token * 4) * 512 + col;
  float4 a = p[0], b = p[512], c = p[1024], d = p[1536];
  out[j] = float4{a.x + b.x + c.x + d.x, a.y + b.y + c.y + d.y,
                  a.z + b.z + c.z + d.z, a.w + b.w + c.w + d.w};
}

extern "C" void kernel_launch(void* const* d_in, const int* in_sizes, int n_in,
                              void* d_out, int out_size, void* d_ws, size_t ws_size,
                              hipStream_t stream) {
  const float* hidden = (const float*)d_in[0];
  const float* tw = (const float*)d_in[1];
  const int* ids = (const int*)d_in[2];
  const int* gup32 = (const int*)d_in[3];        // uint8 packed bytes, uploaded as int32
  const uint32_t* gus = (const uint32_t*)d_in[4];
  const int* dwn32 = (const int*)d_in[5];
  const uint32_t* dsc = (const uint32_t*)d_in[6];
  float* out = (float*)d_out;

  char* ws = (char*)d_ws;
  int* rows = (int*)(ws);                    // 48 KB
  float* rw = (float*)(ws + 49152);          // 48 KB
  int* te = (int*)(ws + 98304);              // 192 B
  u16* xb = (u16*)(ws + 131072);             // 8 MB
  u16* act = (u16*)(ws + 8519680);           // up to 25.2 MB (MAXT*BM rows); ~21 MB written

  // Extended region (only touched if the workspace is big enough):
  const size_t POUT_OFF = 33685504ULL;       // act start + MAXT*BM*FD*2
  const size_t PIDX_OFF = POUT_OFF + (size_t)NPAIR * HD * 4;   // +67 MB
  const size_t WS_NEED = PIDX_OFF + (size_t)MAXT * BM * 4;
  const bool big = ws_size >= WS_NEED;
  float* pout = big ? (float*)(ws + POUT_OFF) : nullptr;
  int* pidx = big ? (int*)(ws + PIDX_OFF) : nullptr;

  cast_kernel<<<dim3(4096), dim3(256), 0, stream>>>(hidden, xb);
  if (!big) zero_kernel<<<dim3(4096), dim3(256), 0, stream>>>((float4*)out);
  route_kernel<<<dim3(1), dim3(256), 0, stream>>>(ids, tw, rows, rw, te, pidx);
  gemm1_kernel<<<dim3(16, MAXT), dim3(256), 0, stream>>>(xb, gup32, gus, rows, rw, te, act);
  gemm2_kernel<<<dim3(16, MAXT), dim3(256), 0, stream>>>(act, dwn32, dsc, rows, pidx, te, out, pout);
  if (big) finalize_kernel<<<dim3(1024 * 1024 / 256), dim3(256), 0, stream>>>((const float4*)pout, (float4*)out);
}

// Round 7
// 539.242 us; speedup vs baseline: 1.0859x; 1.0039x over previous
//
#include <hip/hip_runtime.h>
#include <stdint.h>

#define HD 2048
#define FD 1024
#define NE 16
#define NPAIR 8192
#define BM 256
#define MAXT 48

typedef short bf16x8 __attribute__((ext_vector_type(8)));
typedef float f32x4 __attribute__((ext_vector_type(4)));
typedef unsigned short u16;

static __device__ __forceinline__ u16 f2bf(float f) {
  uint32_t u = __float_as_uint(f);
  u += 0x7FFFu + ((u >> 16) & 1u);
  return (u16)(u >> 16);
}

// Scale-folded byte tables for e2m1 -> bf16 dequant via v_perm.
struct DqTab { uint32_t hA, hB, lA, lB; };

static __device__ __forceinline__ DqTab make_tab(uint32_t sbits) {
  int n = (int)(sbits >> 23) - 127;
  int q = n >> 1;
  uint32_t r = (uint32_t)(n & 1);
  uint32_t mq = (uint32_t)(-q);
  uint32_t sub1 = mq * 0x01010100u;  // entry 0 (zero) untouched
  uint32_t subA = mq * 0x01010101u;
  DqTab t;
  t.hA = (r ? 0x40403F00u : 0x3F3F3F00u) - sub1;
  t.hB = (r ? 0x41414040u : 0x40404040u) - subA;
  t.lA = r ? 0x40008000u : 0xC0800000u;
  t.lB = r ? 0x4000C080u : 0xC0804000u;
  return t;
}

// p: 4 packed fp4 bytes (8 values, low nibble first) -> 4 dwords of bf16 pairs
static __device__ __forceinline__ void dq8(uint32_t p, const DqTab& t, uint32_t* d) {
  uint32_t a = p & 0x0F0F0F0Fu;
  uint32_t b = (p >> 4) & 0x0F0F0F0Fu;
  uint32_t x0 = __builtin_amdgcn_perm(b, a, 0x05010400u);
  uint32_t x1 = __builtin_amdgcn_perm(b, a, 0x07030602u);
  uint32_t m0 = x0 & 0x07070707u;
  uint32_t m1 = x1 & 0x07070707u;
  uint32_t h0 = __builtin_amdgcn_perm(t.hB, t.hA, m0) | ((x0 & 0x08080808u) << 4);
  uint32_t h1 = __builtin_amdgcn_perm(t.hB, t.hA, m1) | ((x1 & 0x08080808u) << 4);
  uint32_t l0 = __builtin_amdgcn_perm(t.lB, t.lA, m0);
  uint32_t l1 = __builtin_amdgcn_perm(t.lB, t.lA, m1);
  d[0] = __builtin_amdgcn_perm(h0, l0, 0x05010400u);
  d[1] = __builtin_amdgcn_perm(h0, l0, 0x07030602u);
  d[2] = __builtin_amdgcn_perm(h1, l1, 0x05010400u);
  d[3] = __builtin_amdgcn_perm(h1, l1, 0x07030602u);
}

static __device__ __forceinline__ uint32_t pack4(int4 v) {
  return (uint32_t)(v.x & 0xFF) | ((uint32_t)(v.y & 0xFF) << 8) |
         ((uint32_t)(v.z & 0xFF) << 16) | ((uint32_t)v.w << 24);
}

// One MFMA B-fragment (8 bf16) from packed LDS (8 u32/row + 1 pad) + scales (2/row).
static __device__ __forceinline__ bf16x8 dqfrag(const uint32_t* pB, const uint32_t* pS,
                                                int row, int j, int q) {
  uint32_t pb = pB[row * 9 + j * 4 + q];
  DqTab t = make_tab(pS[row * 2 + j]);
  uint32_t d[4];
  dq8(pb, t, d);
  union { uint32_t u[4]; bf16x8 v; } cv;
  cv.u[0] = d[0]; cv.u[1] = d[1]; cv.u[2] = d[2]; cv.u[3] = d[3];
  return cv.v;
}

// Direct global->LDS, 16B per lane; dest = wave-uniform base + lane*16.
static __device__ __forceinline__ void glds16(const void* g, void* l) {
  __builtin_amdgcn_global_load_lds(
      (const __attribute__((address_space(1))) uint32_t*)g,
      (__attribute__((address_space(3))) uint32_t*)l, 16, 0, 0);
}

__global__ void cast_kernel(const float* __restrict__ x, u16* __restrict__ xb) {
  int i = blockIdx.x * 256 + threadIdx.x;
  float4 v = ((const float4*)x)[i];
  ushort4 o;
  o.x = f2bf(v.x); o.y = f2bf(v.y); o.z = f2bf(v.z); o.w = f2bf(v.w);
  ((ushort4*)xb)[i] = o;
}

__global__ void zero_kernel(float4* __restrict__ out) {
  out[blockIdx.x * 256 + threadIdx.x] = float4{0.f, 0.f, 0.f, 0.f};
}

__global__ void route_kernel(const int* __restrict__ ids, const float* __restrict__ tw,
                             int* __restrict__ rows, float* __restrict__ rw,
                             int* __restrict__ te, int* __restrict__ pidx) {
  __shared__ int cnt[NE], base[NE], run[NE];
  int tid = threadIdx.x;
  if (tid < NE) { cnt[tid] = 0; run[tid] = 0; }
  __syncthreads();
  for (int i = tid; i < NPAIR; i += 256) atomicAdd(&cnt[ids[i]], 1);
  __syncthreads();
  if (tid == 0) {
    int cum = 0;
    for (int e = 0; e < NE; ++e) {
      base[e] = cum;
      int nt = (cnt[e] + BM - 1) >> 8;
      for (int j = 0; j < nt; ++j) te[(cum >> 8) + j] = e;
      cum += nt << 8;
    }
    for (int t = cum >> 8; t < MAXT; ++t) te[t] = -1;
  }
  __syncthreads();
  for (int i = tid; i < MAXT * BM; i += 256) {
    rows[i] = -1;
    rw[i] = 0.f;
    if (pidx) pidx[i] = -1;
  }
  __syncthreads();
  for (int i = tid; i < NPAIR; i += 256) {
    int e = ids[i];
    int p = base[e] + atomicAdd(&run[e], 1);
    rows[p] = i >> 2;
    rw[p] = tw[i];
    if (pidx) pidx[p] = i;
  }
}

// gate_up GEMM + SwiGLU + routing weight -> act (bf16). BM=256, BN=64+64.
// STRUCTURE: stage = K:64 (2 MFMA K-steps), double-buffered, ONE barrier per stage.
// A: global_load_lds direct (pre-swizzled source, XOR-swizzled reads, linear [row][64] LDS).
// B: 128B-contiguous inflated runs/row -> packed LDS + scales, dequant on read,
//    loaded 2 stages ahead into registers.
__global__ __launch_bounds__(256, 2) void gemm1_kernel(
    const u16* __restrict__ xb, const int* __restrict__ gup32,
    const uint32_t* __restrict__ gus, const int* __restrict__ rows,
    const float* __restrict__ rw, const int* __restrict__ te,
    u16* __restrict__ act) {
  const int tile = blockIdx.y;
  const int e = te[tile];
  if (e < 0) return;
  const int f0 = blockIdx.x * 64;

  __shared__ u16 sA[2][BM * 64];         // 64 KB: [row][64el], 128B stride, swizzled content
  __shared__ uint32_t sBp[2][128 * 9];   // 9.2 KB packed fp4
  __shared__ uint32_t sSc[2][256];       // 2 KB scales (2 per row)
  __shared__ int rows_s[BM];
  __shared__ float rw_s[BM];

  const int tid = threadIdx.x;
  rows_s[tid] = rows[tile * BM + tid];
  rw_s[tid] = rw[tile * BM + tid];
  __syncthreads();

  const int lane = tid & 63;
  const int w = tid >> 6;
  const int q = lane >> 4, c = lane & 15;

  // A glds: wave w stages LDS rows w*64..w*64+63; instr i covers 8 rows x 128B.
  // Lane l -> LDS row (l>>3), seg (l&7); global seg pre-swizzled: (l&7)^(row&7).
  uint32_t aofs[8];
#pragma unroll
  for (int i = 0; i < 8; ++i) {
    const int lrow = w * 64 + i * 8 + (lane >> 3);
    int grow = rows_s[lrow];
    grow = grow < 0 ? 0 : grow;
    aofs[i] = (uint32_t)grow * HD + (uint32_t)(((lane & 7) ^ (lrow & 7)) << 3);
  }

  // B map: for j=0..3 row (tid>>3)+j*32, 16B seg (tid&7) of that row's 128B stage window.
  uint32_t obj[4];
#pragma unroll
  for (int j = 0; j < 4; ++j) {
    const int r_ = (tid >> 3) + j * 32;
    const int o_ = r_ < 64 ? f0 + r_ : 1024 + f0 + (r_ - 64);
    obj[j] = (uint32_t)(e * 2048 + o_) * 1024 + (uint32_t)((tid & 7) << 2);
  }
  const int r_sc = tid >> 1;
  const int o_sc = r_sc < 64 ? f0 + r_sc : 1024 + f0 + (r_sc - 64);
  const uint32_t scb = (uint32_t)(e * 2048 + o_sc) * 64 + (uint32_t)(tid & 1);

  // swizzled in-row read offsets (u16 units) for K-step j=0/1
  const int x0 = ((q * 16) ^ ((c & 7) << 4)) >> 1;
  const int x1 = ((64 + q * 16) ^ ((c & 7) << 4)) >> 1;

  f32x4 Cg[4][4], Cu[4][4];
#pragma unroll
  for (int s = 0; s < 4; ++s)
#pragma unroll
    for (int t2 = 0; t2 < 4; ++t2) {
      Cg[s][t2] = f32x4{0.f, 0.f, 0.f, 0.f};
      Cu[s][t2] = f32x4{0.f, 0.f, 0.f, 0.f};
    }

  int4 breg[4];
  uint32_t sreg;

  // prologue: A(0) glds -> buf0; B(0) -> LDS buf0; B(1) -> regs
  {
#pragma unroll
    for (int i = 0; i < 8; ++i)
      glds16(xb + aofs[i], &sA[0][(w * 64 + i * 8) * 64]);
    int4 b0[4];
#pragma unroll
    for (int j = 0; j < 4; ++j) b0[j] = *(const int4*)(gup32 + obj[j]);
    uint32_t s0 = gus[scb];
#pragma unroll
    for (int j = 0; j < 4; ++j)
      sBp[0][((tid >> 3) + j * 32) * 9 + (tid & 7)] = pack4(b0[j]);
    sSc[0][tid] = s0;
#pragma unroll
    for (int j = 0; j < 4; ++j) breg[j] = *(const int4*)(gup32 + obj[j] + 32);
    sreg = gus[scb + 2];
    __syncthreads();
  }

  for (int s = 0; s < 32; ++s) {
    const int cur = s & 1;
    // stage s+1: A direct-to-LDS + B ds_write (regs loaded one stage ago)
    if (s < 31) {
#pragma unroll
      for (int i = 0; i < 8; ++i)
        glds16(xb + aofs[i] + (uint32_t)(s + 1) * 64, &sA[cur ^ 1][(w * 64 + i * 8) * 64]);
#pragma unroll
      for (int j = 0; j < 4; ++j)
        sBp[cur ^ 1][((tid >> 3) + j * 32) * 9 + (tid & 7)] = pack4(breg[j]);
      sSc[cur ^ 1][tid] = sreg;
    }
    // issue B for stage s+2
    if (s < 30) {
#pragma unroll
      for (int j = 0; j < 4; ++j)
        breg[j] = *(const int4*)(gup32 + obj[j] + (uint32_t)(s + 2) * 32);
      sreg = gus[scb + (uint32_t)(s + 2) * 2];
    }
    // compute stage s: 2 K-steps, 64 MFMA/wave
#pragma unroll
    for (int j = 0; j < 2; ++j) {
      const int xo = j ? x1 : x0;
      bf16x8 af[4];
#pragma unroll
      for (int s4 = 0; s4 < 4; ++s4)
        af[s4] = *(const bf16x8*)&sA[cur][(w * 64 + s4 * 16 + c) * 64 + xo];
#pragma unroll
      for (int t2 = 0; t2 < 4; ++t2) {
        bf16x8 bg = dqfrag(sBp[cur], sSc[cur], t2 * 16 + c, j, q);
        bf16x8 bu = dqfrag(sBp[cur], sSc[cur], 64 + t2 * 16 + c, j, q);
#pragma unroll
        for (int s4 = 0; s4 < 4; ++s4) {
          Cg[s4][t2] = __builtin_amdgcn_mfma_f32_16x16x32_bf16(af[s4], bg, Cg[s4][t2], 0, 0, 0);
          Cu[s4][t2] = __builtin_amdgcn_mfma_f32_16x16x32_bf16(af[s4], bu, Cu[s4][t2], 0, 0, 0);
        }
      }
    }
    __syncthreads();
  }

#pragma unroll
  for (int s = 0; s < 4; ++s) {
    const int mlb = w * 64 + s * 16 + q * 4;
#pragma unroll
    for (int t2 = 0; t2 < 4; ++t2) {
      const int fg = f0 + t2 * 16 + c;
#pragma unroll
      for (int r = 0; r < 4; ++r) {
        const int ml = mlb + r;
        float g = Cg[s][t2][r];
        float u = Cu[s][t2][r];
        float aval = g / (1.f + __expf(-g)) * u * rw_s[ml];
        act[(size_t)(tile * BM + ml) * FD + fg] = f2bf(aval);
      }
    }
  }
}

// down GEMM. BM=256, BN=128. Same stage-dbuf structure (16 stages of K:64).
__global__ __launch_bounds__(256, 2) void gemm2_kernel(
    const u16* __restrict__ act, const int* __restrict__ dwn32,
    const uint32_t* __restrict__ dsc, const int* __restrict__ rows,
    const int* __restrict__ pidx, const int* __restrict__ te,
    float* __restrict__ out, float* __restrict__ pout) {
  const int tile = blockIdx.y;
  const int e = te[tile];
  if (e < 0) return;
  const int h0 = blockIdx.x * 128;

  __shared__ u16 sA[2][BM * 64];
  __shared__ uint32_t sBp[2][128 * 9];
  __shared__ uint32_t sSc[2][256];
  __shared__ int rows_s[BM];
  __shared__ int pidx_s[BM];

  const int tid = threadIdx.x;
  rows_s[tid] = rows[tile * BM + tid];
  pidx_s[tid] = pout ? pidx[tile * BM + tid] : -1;
  __syncthreads();

  const int lane = tid & 63;
  const int w = tid >> 6;
  const int q = lane >> 4, c = lane & 15;

  uint32_t aofs[8];
#pragma unroll
  for (int i = 0; i < 8; ++i) {
    const int lrow = w * 64 + i * 8 + (lane >> 3);
    aofs[i] = (uint32_t)(tile * BM + lrow) * FD + (uint32_t)(((lane & 7) ^ (lrow & 7)) << 3);
  }

  uint32_t obj[4];
#pragma unroll
  for (int j = 0; j < 4; ++j) {
    const int r_ = (tid >> 3) + j * 32;
    obj[j] = (uint32_t)(e * 2048 + h0 + r_) * 512 + (uint32_t)((tid & 7) << 2);
  }
  const uint32_t scb = (uint32_t)(e * 2048 + h0 + (tid >> 1)) * 32 + (uint32_t)(tid & 1);

  const int x0 = ((q * 16) ^ ((c & 7) << 4)) >> 1;
  const int x1 = ((64 + q * 16) ^ ((c & 7) << 4)) >> 1;

  f32x4 Cd[4][8];
#pragma unroll
  for (int s = 0; s < 4; ++s)
#pragma unroll
    for (int t2 = 0; t2 < 8; ++t2) Cd[s][t2] = f32x4{0.f, 0.f, 0.f, 0.f};

  int4 breg[4];
  uint32_t sreg;

  {
#pragma unroll
    for (int i = 0; i < 8; ++i)
      glds16(act + aofs[i], &sA[0][(w * 64 + i * 8) * 64]);
    int4 b0[4];
#pragma unroll
    for (int j = 0; j < 4; ++j) b0[j] = *(const int4*)(dwn32 + obj[j]);
    uint32_t s0 = dsc[scb];
#pragma unroll
    for (int j = 0; j < 4; ++j)
      sBp[0][((tid >> 3) + j * 32) * 9 + (tid & 7)] = pack4(b0[j]);
    sSc[0][tid] = s0;
#pragma unroll
    for (int j = 0; j < 4; ++j) breg[j] = *(const int4*)(dwn32 + obj[j] + 32);
    sreg = dsc[scb + 2];
    __syncthreads();
  }

  for (int s = 0; s < 16; ++s) {
    const int cur = s & 1;
    if (s < 15) {
#pragma unroll
      for (int i = 0; i < 8; ++i)
        glds16(act + aofs[i] + (uint32_t)(s + 1) * 64, &sA[cur ^ 1][(w * 64 + i * 8) * 64]);
#pragma unroll
      for (int j = 0; j < 4; ++j)
        sBp[cur ^ 1][((tid >> 3) + j * 32) * 9 + (tid & 7)] = pack4(breg[j]);
      sSc[cur ^ 1][tid] = sreg;
    }
    if (s < 14) {
#pragma unroll
      for (int j = 0; j < 4; ++j)
        breg[j] = *(const int4*)(dwn32 + obj[j] + (uint32_t)(s + 2) * 32);
      sreg = dsc[scb + (uint32_t)(s + 2) * 2];
    }
#pragma unroll
    for (int j = 0; j < 2; ++j) {
      const int xo = j ? x1 : x0;
      bf16x8 af[4];
#pragma unroll
      for (int s4 = 0; s4 < 4; ++s4)
        af[s4] = *(const bf16x8*)&sA[cur][(w * 64 + s4 * 16 + c) * 64 + xo];
#pragma unroll
      for (int t2 = 0; t2 < 8; ++t2) {
        bf16x8 bf_ = dqfrag(sBp[cur], sSc[cur], t2 * 16 + c, j, q);
#pragma unroll
        for (int s4 = 0; s4 < 4; ++s4)
          Cd[s4][t2] = __builtin_amdgcn_mfma_f32_16x16x32_bf16(af[s4], bf_, Cd[s4][t2], 0, 0, 0);
      }
    }
    __syncthreads();
  }

  if (pout) {
#pragma unroll
    for (int s = 0; s < 4; ++s) {
      const int mlb = w * 64 + s * 16 + q * 4;
#pragma unroll
      for (int t2 = 0; t2 < 8; ++t2) {
        const int hg = h0 + t2 * 16 + c;
#pragma unroll
        for (int r = 0; r < 4; ++r) {
          int prow = pidx_s[mlb + r];
          if (prow >= 0) pout[(size_t)prow * HD + hg] = Cd[s][t2][r];
        }
      }
    }
  } else {
#pragma unroll
    for (int s = 0; s < 4; ++s) {
      const int mlb = w * 64 + s * 16 + q * 4;
#pragma unroll
      for (int t2 = 0; t2 < 8; ++t2) {
        const int hg = h0 + t2 * 16 + c;
#pragma unroll
        for (int r = 0; r < 4; ++r) {
          int token = rows_s[mlb + r];
          if (token >= 0) atomicAdd(&out[(size_t)token * HD + hg], Cd[s][t2][r]);
        }
      }
    }
  }
}

// out[t, :] = sum over the token's 4 pairs of pout[4t+k, :]. Fully coalesced.
__global__ void finalize_kernel(const float4* __restrict__ pout, float4* __restrict__ out) {
  int j = blockIdx.x * 256 + threadIdx.x;   // T*HD/4 = 1,048,576 float4s
  int token = j >> 9;                        // HD/4 = 512 float4 per row
  int col = j & 511;
  const float4* p = pout + ((size_t)token * 4) * 512 + col;
  float4 a = p[0], b = p[512], c = p[1024], d = p[1536];
  out[j] = float4{a.x + b.x + c.x + d.x, a.y + b.y + c.y + d.y,
                  a.z + b.z + c.z + d.z, a.w + b.w + c.w + d.w};
}

extern "C" void kernel_launch(void* const* d_in, const int* in_sizes, int n_in,
                              void* d_out, int out_size, void* d_ws, size_t ws_size,
                              hipStream_t stream) {
  const float* hidden = (const float*)d_in[0];
  const float* tw = (const float*)d_in[1];
  const int* ids = (const int*)d_in[2];
  const int* gup32 = (const int*)d_in[3];        // uint8 packed bytes, uploaded as int32
  const uint32_t* gus = (const uint32_t*)d_in[4];
  const int* dwn32 = (const int*)d_in[5];
  const uint32_t* dsc = (const uint32_t*)d_in[6];
  float* out = (float*)d_out;

  char* ws = (char*)d_ws;
  int* rows = (int*)(ws);                    // 48 KB
  float* rw = (float*)(ws + 49152);          // 48 KB
  int* te = (int*)(ws + 98304);              // 192 B
  u16* xb = (u16*)(ws + 131072);             // 8 MB
  u16* act = (u16*)(ws + 8519680);           // up to 25.2 MB (MAXT*BM rows)

  // Extended region (only touched if the workspace is big enough):
  const size_t POUT_OFF = 33685504ULL;       // act start + MAXT*BM*FD*2
  const size_t PIDX_OFF = POUT_OFF + (size_t)NPAIR * HD * 4;   // +67 MB
  const size_t WS_NEED = PIDX_OFF + (size_t)MAXT * BM * 4;
  const bool big = ws_size >= WS_NEED;
  float* pout = big ? (float*)(ws + POUT_OFF) : nullptr;
  int* pidx = big ? (int*)(ws + PIDX_OFF) : nullptr;

  cast_kernel<<<dim3(4096), dim3(256), 0, stream>>>(hidden, xb);
  if (!big) zero_kernel<<<dim3(4096), dim3(256), 0, stream>>>((float4*)out);
  route_kernel<<<dim3(1), dim3(256), 0, stream>>>(ids, tw, rows, rw, te, pidx);
  gemm1_kernel<<<dim3(16, MAXT), dim3(256), 0, stream>>>(xb, gup32, gus, rows, rw, te, act);
  gemm2_kernel<<<dim3(16, MAXT), dim3(256), 0, stream>>>(act, dwn32, dsc, rows, pidx, te, out, pout);
  if (big) finalize_kernel<<<dim3(1024 * 1024 / 256), dim3(256), 0, stream>>>((const float4*)pout, (float4*)out);
}

// Round 8
// 494.989 us; speedup vs baseline: 1.1830x; 1.0894x over previous
//
#include <hip/hip_runtime.h>
#include <stdint.h>

#define HD 2048
#define FD 1024
#define NE 16
#define NPAIR 8192
#define BM 256
#define MAXT 48

typedef short bf16x8 __attribute__((ext_vector_type(8)));
typedef float f32x4 __attribute__((ext_vector_type(4)));
typedef unsigned short u16;

static __device__ __forceinline__ u16 f2bf(float f) {
  uint32_t u = __float_as_uint(f);
  u += 0x7FFFu + ((u >> 16) & 1u);
  return (u16)(u >> 16);
}

// Scale-folded byte tables for e2m1 -> bf16 dequant via v_perm.
struct DqTab { uint32_t hA, hB, lA, lB; };

static __device__ __forceinline__ DqTab make_tab(uint32_t sbits) {
  int n = (int)(sbits >> 23) - 127;
  int q = n >> 1;
  uint32_t r = (uint32_t)(n & 1);
  uint32_t mq = (uint32_t)(-q);
  uint32_t sub1 = mq * 0x01010100u;  // entry 0 (zero) untouched
  uint32_t subA = mq * 0x01010101u;
  DqTab t;
  t.hA = (r ? 0x40403F00u : 0x3F3F3F00u) - sub1;
  t.hB = (r ? 0x41414040u : 0x40404040u) - subA;
  t.lA = r ? 0x40008000u : 0xC0800000u;
  t.lB = r ? 0x4000C080u : 0xC0804000u;
  return t;
}

// p: 4 packed fp4 bytes (8 values, low nibble first) -> 4 dwords of bf16 pairs
static __device__ __forceinline__ void dq8(uint32_t p, const DqTab& t, uint32_t* d) {
  uint32_t a = p & 0x0F0F0F0Fu;
  uint32_t b = (p >> 4) & 0x0F0F0F0Fu;
  uint32_t x0 = __builtin_amdgcn_perm(b, a, 0x05010400u);
  uint32_t x1 = __builtin_amdgcn_perm(b, a, 0x07030602u);
  uint32_t m0 = x0 & 0x07070707u;
  uint32_t m1 = x1 & 0x07070707u;
  uint32_t h0 = __builtin_amdgcn_perm(t.hB, t.hA, m0) | ((x0 & 0x08080808u) << 4);
  uint32_t h1 = __builtin_amdgcn_perm(t.hB, t.hA, m1) | ((x1 & 0x08080808u) << 4);
  uint32_t l0 = __builtin_amdgcn_perm(t.lB, t.lA, m0);
  uint32_t l1 = __builtin_amdgcn_perm(t.lB, t.lA, m1);
  d[0] = __builtin_amdgcn_perm(h0, l0, 0x05010400u);
  d[1] = __builtin_amdgcn_perm(h0, l0, 0x07030602u);
  d[2] = __builtin_amdgcn_perm(h1, l1, 0x05010400u);
  d[3] = __builtin_amdgcn_perm(h1, l1, 0x07030602u);
}

static __device__ __forceinline__ uint32_t pack4(int4 v) {
  return (uint32_t)(v.x & 0xFF) | ((uint32_t)(v.y & 0xFF) << 8) |
         ((uint32_t)(v.z & 0xFF) << 16) | ((uint32_t)v.w << 24);
}

// One MFMA B-fragment (8 bf16) from packed LDS (8 u32/row + 1 pad) + scales (2/row).
static __device__ __forceinline__ bf16x8 dqfrag(const uint32_t* pB, const uint32_t* pS,
                                                int row, int j, int q) {
  uint32_t pb = pB[row * 9 + j * 4 + q];
  DqTab t = make_tab(pS[row * 2 + j]);
  uint32_t d[4];
  dq8(pb, t, d);
  union { uint32_t u[4]; bf16x8 v; } cv;
  cv.u[0] = d[0]; cv.u[1] = d[1]; cv.u[2] = d[2]; cv.u[3] = d[3];
  return cv.v;
}

// Direct global->LDS, 16B per lane; dest = wave-uniform base + lane*16.
static __device__ __forceinline__ void glds16(const void* g, void* l) {
  __builtin_amdgcn_global_load_lds(
      (const __attribute__((address_space(1))) uint32_t*)g,
      (__attribute__((address_space(3))) uint32_t*)l, 16, 0, 0);
}

__global__ void cast_kernel(const float* __restrict__ x, u16* __restrict__ xb) {
  int i = blockIdx.x * 256 + threadIdx.x;
  float4 v = ((const float4*)x)[i];
  ushort4 o;
  o.x = f2bf(v.x); o.y = f2bf(v.y); o.z = f2bf(v.z); o.w = f2bf(v.w);
  ((ushort4*)xb)[i] = o;
}

__global__ void zero_kernel(float4* __restrict__ out) {
  out[blockIdx.x * 256 + threadIdx.x] = float4{0.f, 0.f, 0.f, 0.f};
}

__global__ void route_kernel(const int* __restrict__ ids, const float* __restrict__ tw,
                             int* __restrict__ rows, float* __restrict__ rw,
                             int* __restrict__ te, int* __restrict__ pidx) {
  __shared__ int cnt[NE], base[NE], run[NE];
  int tid = threadIdx.x;
  if (tid < NE) { cnt[tid] = 0; run[tid] = 0; }
  __syncthreads();
  for (int i = tid; i < NPAIR; i += 256) atomicAdd(&cnt[ids[i]], 1);
  __syncthreads();
  if (tid == 0) {
    int cum = 0;
    for (int e = 0; e < NE; ++e) {
      base[e] = cum;
      int nt = (cnt[e] + BM - 1) >> 8;
      for (int j = 0; j < nt; ++j) te[(cum >> 8) + j] = e;
      cum += nt << 8;
    }
    for (int t = cum >> 8; t < MAXT; ++t) te[t] = -1;
  }
  __syncthreads();
  for (int i = tid; i < MAXT * BM; i += 256) {
    rows[i] = -1;
    rw[i] = 0.f;
    if (pidx) pidx[i] = -1;
  }
  __syncthreads();
  for (int i = tid; i < NPAIR; i += 256) {
    int e = ids[i];
    int p = base[e] + atomicAdd(&run[e], 1);
    rows[p] = i >> 2;
    rw[p] = tw[i];
    if (pidx) pidx[p] = i;
  }
}

// gate_up GEMM + SwiGLU + routing weight -> act (bf16). BM=256, BN=64+64.
// Stage = K:64, double-buffered, ONE barrier per stage; A via global_load_lds
// (pre-swizzled src, XOR-swizzled reads); B packed in LDS, dequant on read.
// WAVE DECOMPOSITION 2Mx2N: wave (wr,wc) owns 128 rows x (32 gate + 32 up cols).
// Per wave per K-step: 4 dqfrags (was 8), each feeding 16 MFMAs (was 8).
__global__ __launch_bounds__(256, 2) void gemm1_kernel(
    const u16* __restrict__ xb, const int* __restrict__ gup32,
    const uint32_t* __restrict__ gus, const int* __restrict__ rows,
    const float* __restrict__ rw, const int* __restrict__ te,
    u16* __restrict__ act) {
  const int tile = blockIdx.y;
  const int e = te[tile];
  if (e < 0) return;
  const int f0 = blockIdx.x * 64;

  __shared__ u16 sA[2][BM * 64];         // 64 KB: [row][64el], swizzled content
  __shared__ uint32_t sBp[2][128 * 9];   // 9.2 KB packed fp4
  __shared__ uint32_t sSc[2][256];       // 2 KB scales (2 per row)
  __shared__ int rows_s[BM];
  __shared__ float rw_s[BM];

  const int tid = threadIdx.x;
  rows_s[tid] = rows[tile * BM + tid];
  rw_s[tid] = rw[tile * BM + tid];
  __syncthreads();

  const int lane = tid & 63;
  const int w = tid >> 6;
  const int wr = w >> 1;   // 0..1 M-half (128 rows)
  const int wc = w & 1;    // 0..1 N-half (32 gate + 32 up cols)
  const int q = lane >> 4, c = lane & 15;

  // A glds staging: wave w stages LDS rows w*64..w*64+63 (map independent of compute).
  uint32_t aofs[8];
#pragma unroll
  for (int i = 0; i < 8; ++i) {
    const int lrow = w * 64 + i * 8 + (lane >> 3);
    int grow = rows_s[lrow];
    grow = grow < 0 ? 0 : grow;
    aofs[i] = (uint32_t)grow * HD + (uint32_t)(((lane & 7) ^ (lrow & 7)) << 3);
  }

  // B staging map: row (tid>>3)+j*32, 16B seg (tid&7) of the 128B stage window.
  uint32_t obj[4];
#pragma unroll
  for (int j = 0; j < 4; ++j) {
    const int r_ = (tid >> 3) + j * 32;
    const int o_ = r_ < 64 ? f0 + r_ : 1024 + f0 + (r_ - 64);
    obj[j] = (uint32_t)(e * 2048 + o_) * 1024 + (uint32_t)((tid & 7) << 2);
  }
  const int r_sc = tid >> 1;
  const int o_sc = r_sc < 64 ? f0 + r_sc : 1024 + f0 + (r_sc - 64);
  const uint32_t scb = (uint32_t)(e * 2048 + o_sc) * 64 + (uint32_t)(tid & 1);

  // swizzled in-row read offsets (u16 units) for K-step j=0/1
  const int x0 = ((q * 16) ^ ((c & 7) << 4)) >> 1;
  const int x1 = ((64 + q * 16) ^ ((c & 7) << 4)) >> 1;

  f32x4 Cg[8][2], Cu[8][2];
#pragma unroll
  for (int s = 0; s < 8; ++s)
#pragma unroll
    for (int t2 = 0; t2 < 2; ++t2) {
      Cg[s][t2] = f32x4{0.f, 0.f, 0.f, 0.f};
      Cu[s][t2] = f32x4{0.f, 0.f, 0.f, 0.f};
    }

  int4 breg[4];
  uint32_t sreg;

  // prologue: A(0) glds -> buf0; B(0) -> LDS buf0; B(1) -> regs
  {
#pragma unroll
    for (int i = 0; i < 8; ++i)
      glds16(xb + aofs[i], &sA[0][(w * 64 + i * 8) * 64]);
    int4 b0[4];
#pragma unroll
    for (int j = 0; j < 4; ++j) b0[j] = *(const int4*)(gup32 + obj[j]);
    uint32_t s0 = gus[scb];
#pragma unroll
    for (int j = 0; j < 4; ++j)
      sBp[0][((tid >> 3) + j * 32) * 9 + (tid & 7)] = pack4(b0[j]);
    sSc[0][tid] = s0;
#pragma unroll
    for (int j = 0; j < 4; ++j) breg[j] = *(const int4*)(gup32 + obj[j] + 32);
    sreg = gus[scb + 2];
    __syncthreads();
  }

  for (int s = 0; s < 32; ++s) {
    const int cur = s & 1;
    if (s < 31) {
#pragma unroll
      for (int i = 0; i < 8; ++i)
        glds16(xb + aofs[i] + (uint32_t)(s + 1) * 64, &sA[cur ^ 1][(w * 64 + i * 8) * 64]);
#pragma unroll
      for (int j = 0; j < 4; ++j)
        sBp[cur ^ 1][((tid >> 3) + j * 32) * 9 + (tid & 7)] = pack4(breg[j]);
      sSc[cur ^ 1][tid] = sreg;
    }
    if (s < 30) {
#pragma unroll
      for (int j = 0; j < 4; ++j)
        breg[j] = *(const int4*)(gup32 + obj[j] + (uint32_t)(s + 2) * 32);
      sreg = gus[scb + (uint32_t)(s + 2) * 2];
    }
    // compute stage s: 2 K-steps; per K-step 4 dqfrags feed 32 MFMAs
#pragma unroll
    for (int j = 0; j < 2; ++j) {
      const int xo = j ? x1 : x0;
      bf16x8 bg[2], bu[2];
#pragma unroll
      for (int t2 = 0; t2 < 2; ++t2) {
        bg[t2] = dqfrag(sBp[cur], sSc[cur], wc * 32 + t2 * 16 + c, j, q);
        bu[t2] = dqfrag(sBp[cur], sSc[cur], 64 + wc * 32 + t2 * 16 + c, j, q);
      }
#pragma unroll
      for (int s4 = 0; s4 < 8; ++s4) {
        bf16x8 af = *(const bf16x8*)&sA[cur][(wr * 128 + s4 * 16 + c) * 64 + xo];
#pragma unroll
        for (int t2 = 0; t2 < 2; ++t2) {
          Cg[s4][t2] = __builtin_amdgcn_mfma_f32_16x16x32_bf16(af, bg[t2], Cg[s4][t2], 0, 0, 0);
          Cu[s4][t2] = __builtin_amdgcn_mfma_f32_16x16x32_bf16(af, bu[t2], Cu[s4][t2], 0, 0, 0);
        }
      }
    }
    __syncthreads();
  }

#pragma unroll
  for (int s4 = 0; s4 < 8; ++s4) {
    const int mlb = wr * 128 + s4 * 16 + q * 4;
#pragma unroll
    for (int t2 = 0; t2 < 2; ++t2) {
      const int fg = f0 + wc * 32 + t2 * 16 + c;
#pragma unroll
      for (int r = 0; r < 4; ++r) {
        const int ml = mlb + r;
        float g = Cg[s4][t2][r];
        float u = Cu[s4][t2][r];
        float aval = g / (1.f + __expf(-g)) * u * rw_s[ml];
        act[(size_t)(tile * BM + ml) * FD + fg] = f2bf(aval);
      }
    }
  }
}

// down GEMM. BM=256, BN=128. Same structure; 2Mx2N wave decomposition:
// wave (wr,wc) owns 128 rows x 64 cols; 4 dqfrags/K-step (was 8).
__global__ __launch_bounds__(256, 2) void gemm2_kernel(
    const u16* __restrict__ act, const int* __restrict__ dwn32,
    const uint32_t* __restrict__ dsc, const int* __restrict__ rows,
    const int* __restrict__ pidx, const int* __restrict__ te,
    float* __restrict__ out, float* __restrict__ pout) {
  const int tile = blockIdx.y;
  const int e = te[tile];
  if (e < 0) return;
  const int h0 = blockIdx.x * 128;

  __shared__ u16 sA[2][BM * 64];
  __shared__ uint32_t sBp[2][128 * 9];
  __shared__ uint32_t sSc[2][256];
  __shared__ int rows_s[BM];
  __shared__ int pidx_s[BM];

  const int tid = threadIdx.x;
  rows_s[tid] = rows[tile * BM + tid];
  pidx_s[tid] = pout ? pidx[tile * BM + tid] : -1;
  __syncthreads();

  const int lane = tid & 63;
  const int w = tid >> 6;
  const int wr = w >> 1;   // 0..1
  const int wc = w & 1;    // 0..1
  const int q = lane >> 4, c = lane & 15;

  uint32_t aofs[8];
#pragma unroll
  for (int i = 0; i < 8; ++i) {
    const int lrow = w * 64 + i * 8 + (lane >> 3);
    aofs[i] = (uint32_t)(tile * BM + lrow) * FD + (uint32_t)(((lane & 7) ^ (lrow & 7)) << 3);
  }

  uint32_t obj[4];
#pragma unroll
  for (int j = 0; j < 4; ++j) {
    const int r_ = (tid >> 3) + j * 32;
    obj[j] = (uint32_t)(e * 2048 + h0 + r_) * 512 + (uint32_t)((tid & 7) << 2);
  }
  const uint32_t scb = (uint32_t)(e * 2048 + h0 + (tid >> 1)) * 32 + (uint32_t)(tid & 1);

  const int x0 = ((q * 16) ^ ((c & 7) << 4)) >> 1;
  const int x1 = ((64 + q * 16) ^ ((c & 7) << 4)) >> 1;

  f32x4 Cd[8][4];
#pragma unroll
  for (int s = 0; s < 8; ++s)
#pragma unroll
    for (int t2 = 0; t2 < 4; ++t2) Cd[s][t2] = f32x4{0.f, 0.f, 0.f, 0.f};

  int4 breg[4];
  uint32_t sreg;

  {
#pragma unroll
    for (int i = 0; i < 8; ++i)
      glds16(act + aofs[i], &sA[0][(w * 64 + i * 8) * 64]);
    int4 b0[4];
#pragma unroll
    for (int j = 0; j < 4; ++j) b0[j] = *(const int4*)(dwn32 + obj[j]);
    uint32_t s0 = dsc[scb];
#pragma unroll
    for (int j = 0; j < 4; ++j)
      sBp[0][((tid >> 3) + j * 32) * 9 + (tid & 7)] = pack4(b0[j]);
    sSc[0][tid] = s0;
#pragma unroll
    for (int j = 0; j < 4; ++j) breg[j] = *(const int4*)(dwn32 + obj[j] + 32);
    sreg = dsc[scb + 2];
    __syncthreads();
  }

  for (int s = 0; s < 16; ++s) {
    const int cur = s & 1;
    if (s < 15) {
#pragma unroll
      for (int i = 0; i < 8; ++i)
        glds16(act + aofs[i] + (uint32_t)(s + 1) * 64, &sA[cur ^ 1][(w * 64 + i * 8) * 64]);
#pragma unroll
      for (int j = 0; j < 4; ++j)
        sBp[cur ^ 1][((tid >> 3) + j * 32) * 9 + (tid & 7)] = pack4(breg[j]);
      sSc[cur ^ 1][tid] = sreg;
    }
    if (s < 14) {
#pragma unroll
      for (int j = 0; j < 4; ++j)
        breg[j] = *(const int4*)(dwn32 + obj[j] + (uint32_t)(s + 2) * 32);
      sreg = dsc[scb + (uint32_t)(s + 2) * 2];
    }
#pragma unroll
    for (int j = 0; j < 2; ++j) {
      const int xo = j ? x1 : x0;
      bf16x8 bf_[4];
#pragma unroll
      for (int t2 = 0; t2 < 4; ++t2)
        bf_[t2] = dqfrag(sBp[cur], sSc[cur], wc * 64 + t2 * 16 + c, j, q);
#pragma unroll
      for (int s4 = 0; s4 < 8; ++s4) {
        bf16x8 af = *(const bf16x8*)&sA[cur][(wr * 128 + s4 * 16 + c) * 64 + xo];
#pragma unroll
        for (int t2 = 0; t2 < 4; ++t2)
          Cd[s4][t2] = __builtin_amdgcn_mfma_f32_16x16x32_bf16(af, bf_[t2], Cd[s4][t2], 0, 0, 0);
      }
    }
    __syncthreads();
  }

  if (pout) {
#pragma unroll
    for (int s4 = 0; s4 < 8; ++s4) {
      const int mlb = wr * 128 + s4 * 16 + q * 4;
#pragma unroll
      for (int t2 = 0; t2 < 4; ++t2) {
        const int hg = h0 + wc * 64 + t2 * 16 + c;
#pragma unroll
        for (int r = 0; r < 4; ++r) {
          int prow = pidx_s[mlb + r];
          if (prow >= 0) pout[(size_t)prow * HD + hg] = Cd[s4][t2][r];
        }
      }
    }
  } else {
#pragma unroll
    for (int s4 = 0; s4 < 8; ++s4) {
      const int mlb = wr * 128 + s4 * 16 + q * 4;
#pragma unroll
      for (int t2 = 0; t2 < 4; ++t2) {
        const int hg = h0 + wc * 64 + t2 * 16 + c;
#pragma unroll
        for (int r = 0; r < 4; ++r) {
          int token = rows_s[mlb + r];
          if (token >= 0) atomicAdd(&out[(size_t)token * HD + hg], Cd[s4][t2][r]);
        }
      }
    }
  }
}

// out[t, :] = sum over the token's 4 pairs of pout[4t+k, :]. Fully coalesced.
__global__ void finalize_kernel(const float4* __restrict__ pout, float4* __restrict__ out) {
  int j = blockIdx.x * 256 + threadIdx.x;   // T*HD/4 = 1,048,576 float4s
  int token = j >> 9;                        // HD/4 = 512 float4 per row
  int col = j & 511;
  const float4* p = pout + ((size_t)token * 4) * 512 + col;
  float4 a = p[0], b = p[512], c = p[1024], d = p[1536];
  out[j] = float4{a.x + b.x + c.x + d.x, a.y + b.y + c.y + d.y,
                  a.z + b.z + c.z + d.z, a.w + b.w + c.w + d.w};
}

extern "C" void kernel_launch(void* const* d_in, const int* in_sizes, int n_in,
                              void* d_out, int out_size, void* d_ws, size_t ws_size,
                              hipStream_t stream) {
  const float* hidden = (const float*)d_in[0];
  const float* tw = (const float*)d_in[1];
  const int* ids = (const int*)d_in[2];
  const int* gup32 = (const int*)d_in[3];        // uint8 packed bytes, uploaded as int32
  const uint32_t* gus = (const uint32_t*)d_in[4];
  const int* dwn32 = (const int*)d_in[5];
  const uint32_t* dsc = (const uint32_t*)d_in[6];
  float* out = (float*)d_out;

  char* ws = (char*)d_ws;
  int* rows = (int*)(ws);                    // 48 KB
  float* rw = (float*)(ws + 49152);          // 48 KB
  int* te = (int*)(ws + 98304);              // 192 B
  u16* xb = (u16*)(ws + 131072);             // 8 MB
  u16* act = (u16*)(ws + 8519680);           // up to 25.2 MB (MAXT*BM rows)

  // Extended region (only touched if the workspace is big enough):
  const size_t POUT_OFF = 33685504ULL;       // act start + MAXT*BM*FD*2
  const size_t PIDX_OFF = POUT_OFF + (size_t)NPAIR * HD * 4;   // +67 MB
  const size_t WS_NEED = PIDX_OFF + (size_t)MAXT * BM * 4;
  const bool big = ws_size >= WS_NEED;
  float* pout = big ? (float*)(ws + POUT_OFF) : nullptr;
  int* pidx = big ? (int*)(ws + PIDX_OFF) : nullptr;

  cast_kernel<<<dim3(4096), dim3(256), 0, stream>>>(hidden, xb);
  if (!big) zero_kernel<<<dim3(4096), dim3(256), 0, stream>>>((float4*)out);
  route_kernel<<<dim3(1), dim3(256), 0, stream>>>(ids, tw, rows, rw, te, pidx);
  gemm1_kernel<<<dim3(16, MAXT), dim3(256), 0, stream>>>(xb, gup32, gus, rows, rw, te, act);
  gemm2_kernel<<<dim3(16, MAXT), dim3(256), 0, stream>>>(act, dwn32, dsc, rows, pidx, te, out, pout);
  if (big) finalize_kernel<<<dim3(1024 * 1024 / 256), dim3(256), 0, stream>>>((const float4*)pout, (float4*)out);
}

// Round 10
// 488.334 us; speedup vs baseline: 1.1991x; 1.0136x over previous
//
#include <hip/hip_runtime.h>
#include <stdint.h>

#define HD 2048
#define FD 1024
#define NE 16
#define NPAIR 8192
#define BM 256
#define MAXT 48

typedef short bf16x8 __attribute__((ext_vector_type(8)));
typedef float f32x4 __attribute__((ext_vector_type(4)));
typedef unsigned short u16;

static __device__ __forceinline__ u16 f2bf(float f) {
  uint32_t u = __float_as_uint(f);
  u += 0x7FFFu + ((u >> 16) & 1u);
  return (u16)(u >> 16);
}

// Counted barrier (T4): drain glds A-loads (oldest 8) + all LDS ops, leave the
// 5 newest vmem ops (next-next-stage B prefetch) in flight across the barrier.
// Cross-wave safety: every wave drains its OWN glds + ds_writes before s_barrier;
// the ops left in flight are register-destined and same-wave-consumed.
static __device__ __forceinline__ void sbar_cnt() {
  __builtin_amdgcn_sched_barrier(0);
  asm volatile("s_waitcnt vmcnt(5) lgkmcnt(0)" ::: "memory");
  __builtin_amdgcn_s_barrier();
  __builtin_amdgcn_sched_barrier(0);
}
static __device__ __forceinline__ void sbar_all() {
  __builtin_amdgcn_sched_barrier(0);
  asm volatile("s_waitcnt vmcnt(0) lgkmcnt(0)" ::: "memory");
  __builtin_amdgcn_s_barrier();
  __builtin_amdgcn_sched_barrier(0);
}

// Scale-folded byte tables for e2m1 -> bf16 dequant via v_perm.
struct DqTab { uint32_t hA, hB, lA, lB; };

static __device__ __forceinline__ DqTab make_tab(uint32_t sbits) {
  int n = (int)(sbits >> 23) - 127;
  int q = n >> 1;
  uint32_t r = (uint32_t)(n & 1);
  uint32_t mq = (uint32_t)(-q);
  uint32_t sub1 = mq * 0x01010100u;  // entry 0 (zero) untouched
  uint32_t subA = mq * 0x01010101u;
  DqTab t;
  t.hA = (r ? 0x40403F00u : 0x3F3F3F00u) - sub1;
  t.hB = (r ? 0x41414040u : 0x40404040u) - subA;
  t.lA = r ? 0x40008000u : 0xC0800000u;
  t.lB = r ? 0x4000C080u : 0xC0804000u;
  return t;
}

// p: 4 packed fp4 bytes (8 values, low nibble first) -> 4 dwords of bf16 pairs
static __device__ __forceinline__ void dq8(uint32_t p, const DqTab& t, uint32_t* d) {
  uint32_t a = p & 0x0F0F0F0Fu;
  uint32_t b = (p >> 4) & 0x0F0F0F0Fu;
  uint32_t x0 = __builtin_amdgcn_perm(b, a, 0x05010400u);
  uint32_t x1 = __builtin_amdgcn_perm(b, a, 0x07030602u);
  uint32_t m0 = x0 & 0x07070707u;
  uint32_t m1 = x1 & 0x07070707u;
  uint32_t h0 = __builtin_amdgcn_perm(t.hB, t.hA, m0) | ((x0 & 0x08080808u) << 4);
  uint32_t h1 = __builtin_amdgcn_perm(t.hB, t.hA, m1) | ((x1 & 0x08080808u) << 4);
  uint32_t l0 = __builtin_amdgcn_perm(t.lB, t.lA, m0);
  uint32_t l1 = __builtin_amdgcn_perm(t.lB, t.lA, m1);
  d[0] = __builtin_amdgcn_perm(h0, l0, 0x05010400u);
  d[1] = __builtin_amdgcn_perm(h0, l0, 0x07030602u);
  d[2] = __builtin_amdgcn_perm(h1, l1, 0x05010400u);
  d[3] = __builtin_amdgcn_perm(h1, l1, 0x07030602u);
}

static __device__ __forceinline__ uint32_t pack4(int4 v) {
  return (uint32_t)(v.x & 0xFF) | ((uint32_t)(v.y & 0xFF) << 8) |
         ((uint32_t)(v.z & 0xFF) << 16) | ((uint32_t)v.w << 24);
}

// One MFMA B-fragment (8 bf16) from packed LDS (8 u32/row + 1 pad) + scales (2/row).
static __device__ __forceinline__ bf16x8 dqfrag(const uint32_t* pB, const uint32_t* pS,
                                                int row, int j, int q) {
  uint32_t pb = pB[row * 9 + j * 4 + q];
  DqTab t = make_tab(pS[row * 2 + j]);
  uint32_t d[4];
  dq8(pb, t, d);
  union { uint32_t u[4]; bf16x8 v; } cv;
  cv.u[0] = d[0]; cv.u[1] = d[1]; cv.u[2] = d[2]; cv.u[3] = d[3];
  return cv.v;
}

// Direct global->LDS, 16B per lane; dest = wave-uniform base + lane*16.
static __device__ __forceinline__ void glds16(const void* g, void* l) {
  __builtin_amdgcn_global_load_lds(
      (const __attribute__((address_space(1))) uint32_t*)g,
      (__attribute__((address_space(3))) uint32_t*)l, 16, 0, 0);
}

__global__ void cast_kernel(const float* __restrict__ x, u16* __restrict__ xb) {
  int i = blockIdx.x * 256 + threadIdx.x;
  float4 v = ((const float4*)x)[i];
  ushort4 o;
  o.x = f2bf(v.x); o.y = f2bf(v.y); o.z = f2bf(v.z); o.w = f2bf(v.w);
  ((ushort4*)xb)[i] = o;
}

__global__ void zero_kernel(float4* __restrict__ out) {
  out[blockIdx.x * 256 + threadIdx.x] = float4{0.f, 0.f, 0.f, 0.f};
}

__global__ void route_kernel(const int* __restrict__ ids, const float* __restrict__ tw,
                             int* __restrict__ rows, float* __restrict__ rw,
                             int* __restrict__ te, int* __restrict__ pidx) {
  __shared__ int cnt[NE], base[NE], run[NE];
  int tid = threadIdx.x;
  if (tid < NE) { cnt[tid] = 0; run[tid] = 0; }
  __syncthreads();
  for (int i = tid; i < NPAIR; i += 256) atomicAdd(&cnt[ids[i]], 1);
  __syncthreads();
  if (tid == 0) {
    int cum = 0;
    for (int e = 0; e < NE; ++e) {
      base[e] = cum;
      int nt = (cnt[e] + BM - 1) >> 8;
      for (int j = 0; j < nt; ++j) te[(cum >> 8) + j] = e;
      cum += nt << 8;
    }
    for (int t = cum >> 8; t < MAXT; ++t) te[t] = -1;
  }
  __syncthreads();
  for (int i = tid; i < MAXT * BM; i += 256) {
    rows[i] = -1;
    rw[i] = 0.f;
    if (pidx) pidx[i] = -1;
  }
  __syncthreads();
  for (int i = tid; i < NPAIR; i += 256) {
    int e = ids[i];
    int p = base[e] + atomicAdd(&run[e], 1);
    rows[p] = i >> 2;
    rw[p] = tw[i];
    if (pidx) pidx[p] = i;
  }
}

// gate_up GEMM + SwiGLU + routing weight -> act (bf16). BM=256, BN=64+64.
// Stage = K:64, dbuf, ONE barrier per stage — now a COUNTED barrier: the
// next-next-stage B prefetch (5 vmem ops, newest) stays in flight across it.
// A via global_load_lds (pre-swizzled src, XOR-swizzled reads); B packed LDS,
// dequant on read; 2Mx2N wave decomposition.
__global__ __launch_bounds__(256, 2) void gemm1_kernel(
    const u16* __restrict__ xb, const int* __restrict__ gup32,
    const uint32_t* __restrict__ gus, const int* __restrict__ rows,
    const float* __restrict__ rw, const int* __restrict__ te,
    u16* __restrict__ act) {
  const int tile = blockIdx.y;
  const int e = te[tile];
  if (e < 0) return;
  const int f0 = blockIdx.x * 64;

  __shared__ u16 sA[2][BM * 64];         // 64 KB: [row][64el], swizzled content
  __shared__ uint32_t sBp[2][128 * 9];   // 9.2 KB packed fp4
  __shared__ uint32_t sSc[2][256];       // 2 KB scales (2 per row)
  __shared__ int rows_s[BM];
  __shared__ float rw_s[BM];

  const int tid = threadIdx.x;
  rows_s[tid] = rows[tile * BM + tid];
  rw_s[tid] = rw[tile * BM + tid];
  __syncthreads();

  const int lane = tid & 63;
  const int w = tid >> 6;
  const int wr = w >> 1;   // 0..1 M-half (128 rows)
  const int wc = w & 1;    // 0..1 N-half (32 gate + 32 up cols)
  const int q = lane >> 4, c = lane & 15;

  // A glds staging: wave w stages LDS rows w*64..w*64+63.
  uint32_t aofs[8];
#pragma unroll
  for (int i = 0; i < 8; ++i) {
    const int lrow = w * 64 + i * 8 + (lane >> 3);
    int grow = rows_s[lrow];
    grow = grow < 0 ? 0 : grow;
    aofs[i] = (uint32_t)grow * HD + (uint32_t)(((lane & 7) ^ (lrow & 7)) << 3);
  }

  // B staging map: row (tid>>3)+j*32, 16B seg (tid&7) of the 128B stage window.
  uint32_t obj[4];
#pragma unroll
  for (int j = 0; j < 4; ++j) {
    const int r_ = (tid >> 3) + j * 32;
    const int o_ = r_ < 64 ? f0 + r_ : 1024 + f0 + (r_ - 64);
    obj[j] = (uint32_t)(e * 2048 + o_) * 1024 + (uint32_t)((tid & 7) << 2);
  }
  const int r_sc = tid >> 1;
  const int o_sc = r_sc < 64 ? f0 + r_sc : 1024 + f0 + (r_sc - 64);
  const uint32_t scb = (uint32_t)(e * 2048 + o_sc) * 64 + (uint32_t)(tid & 1);

  // swizzled in-row read offsets (u16 units) for K-step j=0/1
  const int x0 = ((q * 16) ^ ((c & 7) << 4)) >> 1;
  const int x1 = ((64 + q * 16) ^ ((c & 7) << 4)) >> 1;

  f32x4 Cg[8][2], Cu[8][2];
#pragma unroll
  for (int s = 0; s < 8; ++s)
#pragma unroll
    for (int t2 = 0; t2 < 2; ++t2) {
      Cg[s][t2] = f32x4{0.f, 0.f, 0.f, 0.f};
      Cu[s][t2] = f32x4{0.f, 0.f, 0.f, 0.f};
    }

  int4 breg[4];
  uint32_t sreg;

  // prologue: A(0) glds -> buf0; B(0) -> LDS buf0; B(1) -> regs. Full drain once.
  {
#pragma unroll
    for (int i = 0; i < 8; ++i)
      glds16(xb + aofs[i], &sA[0][(w * 64 + i * 8) * 64]);
    int4 b0[4];
#pragma unroll
    for (int j = 0; j < 4; ++j) b0[j] = *(const int4*)(gup32 + obj[j]);
    uint32_t s0 = gus[scb];
#pragma unroll
    for (int j = 0; j < 4; ++j)
      sBp[0][((tid >> 3) + j * 32) * 9 + (tid & 7)] = pack4(b0[j]);
    sSc[0][tid] = s0;
#pragma unroll
    for (int j = 0; j < 4; ++j) breg[j] = *(const int4*)(gup32 + obj[j] + 32);
    sreg = gus[scb + 2];
    sbar_all();
  }

  for (int s = 0; s < 32; ++s) {
    const int cur = s & 1;
    // [oldest vmem this stage] A glds for s+1, + B ds_write (regs from s-1 issue)
    if (s < 31) {
#pragma unroll
      for (int i = 0; i < 8; ++i)
        glds16(xb + aofs[i] + (uint32_t)(s + 1) * 64, &sA[cur ^ 1][(w * 64 + i * 8) * 64]);
#pragma unroll
      for (int j = 0; j < 4; ++j)
        sBp[cur ^ 1][((tid >> 3) + j * 32) * 9 + (tid & 7)] = pack4(breg[j]);
      sSc[cur ^ 1][tid] = sreg;
    }
    // pin: glds must be OLDER than the B issue below (vmcnt counting relies on it)
    __builtin_amdgcn_sched_barrier(0);
    // [newest vmem this stage] B loads for s+2 — these stay in flight across the barrier
    if (s < 30) {
#pragma unroll
      for (int j = 0; j < 4; ++j)
        breg[j] = *(const int4*)(gup32 + obj[j] + (uint32_t)(s + 2) * 32);
      sreg = gus[scb + (uint32_t)(s + 2) * 2];
    }
    // compute stage s: LDS-only ops
#pragma unroll
    for (int j = 0; j < 2; ++j) {
      const int xo = j ? x1 : x0;
      bf16x8 bg[2], bu[2];
#pragma unroll
      for (int t2 = 0; t2 < 2; ++t2) {
        bg[t2] = dqfrag(sBp[cur], sSc[cur], wc * 32 + t2 * 16 + c, j, q);
        bu[t2] = dqfrag(sBp[cur], sSc[cur], 64 + wc * 32 + t2 * 16 + c, j, q);
      }
#pragma unroll
      for (int s4 = 0; s4 < 8; ++s4) {
        bf16x8 af = *(const bf16x8*)&sA[cur][(wr * 128 + s4 * 16 + c) * 64 + xo];
#pragma unroll
        for (int t2 = 0; t2 < 2; ++t2) {
          Cg[s4][t2] = __builtin_amdgcn_mfma_f32_16x16x32_bf16(af, bg[t2], Cg[s4][t2], 0, 0, 0);
          Cu[s4][t2] = __builtin_amdgcn_mfma_f32_16x16x32_bf16(af, bu[t2], Cu[s4][t2], 0, 0, 0);
        }
      }
    }
    // counted barrier while B(s+2) prefetch stays in flight; tail stages drain all
    if (s < 30) sbar_cnt(); else sbar_all();
  }

#pragma unroll
  for (int s4 = 0; s4 < 8; ++s4) {
    const int mlb = wr * 128 + s4 * 16 + q * 4;
#pragma unroll
    for (int t2 = 0; t2 < 2; ++t2) {
      const int fg = f0 + wc * 32 + t2 * 16 + c;
#pragma unroll
      for (int r = 0; r < 4; ++r) {
        const int ml = mlb + r;
        float g = Cg[s4][t2][r];
        float u = Cu[s4][t2][r];
        float aval = g / (1.f + __expf(-g)) * u * rw_s[ml];
        act[(size_t)(tile * BM + ml) * FD + fg] = f2bf(aval);
      }
    }
  }
}

// down GEMM. BM=256, BN=128. Same counted-barrier structure; 2Mx2N waves.
__global__ __launch_bounds__(256, 2) void gemm2_kernel(
    const u16* __restrict__ act, const int* __restrict__ dwn32,
    const uint32_t* __restrict__ dsc, const int* __restrict__ rows,
    const int* __restrict__ pidx, const int* __restrict__ te,
    float* __restrict__ out, float* __restrict__ pout) {
  const int tile = blockIdx.y;
  const int e = te[tile];
  if (e < 0) return;
  const int h0 = blockIdx.x * 128;

  __shared__ u16 sA[2][BM * 64];
  __shared__ uint32_t sBp[2][128 * 9];
  __shared__ uint32_t sSc[2][256];
  __shared__ int rows_s[BM];
  __shared__ int pidx_s[BM];

  const int tid = threadIdx.x;
  rows_s[tid] = rows[tile * BM + tid];
  pidx_s[tid] = pout ? pidx[tile * BM + tid] : -1;
  __syncthreads();

  const int lane = tid & 63;
  const int w = tid >> 6;
  const int wr = w >> 1;   // 0..1
  const int wc = w & 1;    // 0..1
  const int q = lane >> 4, c = lane & 15;

  uint32_t aofs[8];
#pragma unroll
  for (int i = 0; i < 8; ++i) {
    const int lrow = w * 64 + i * 8 + (lane >> 3);
    aofs[i] = (uint32_t)(tile * BM + lrow) * FD + (uint32_t)(((lane & 7) ^ (lrow & 7)) << 3);
  }

  uint32_t obj[4];
#pragma unroll
  for (int j = 0; j < 4; ++j) {
    const int r_ = (tid >> 3) + j * 32;
    obj[j] = (uint32_t)(e * 2048 + h0 + r_) * 512 + (uint32_t)((tid & 7) << 2);
  }
  const uint32_t scb = (uint32_t)(e * 2048 + h0 + (tid >> 1)) * 32 + (uint32_t)(tid & 1);

  const int x0 = ((q * 16) ^ ((c & 7) << 4)) >> 1;
  const int x1 = ((64 + q * 16) ^ ((c & 7) << 4)) >> 1;

  f32x4 Cd[8][4];
#pragma unroll
  for (int s = 0; s < 8; ++s)
#pragma unroll
    for (int t2 = 0; t2 < 4; ++t2) Cd[s][t2] = f32x4{0.f, 0.f, 0.f, 0.f};

  int4 breg[4];
  uint32_t sreg;

  {
#pragma unroll
    for (int i = 0; i < 8; ++i)
      glds16(act + aofs[i], &sA[0][(w * 64 + i * 8) * 64]);
    int4 b0[4];
#pragma unroll
    for (int j = 0; j < 4; ++j) b0[j] = *(const int4*)(dwn32 + obj[j]);
    uint32_t s0 = dsc[scb];
#pragma unroll
    for (int j = 0; j < 4; ++j)
      sBp[0][((tid >> 3) + j * 32) * 9 + (tid & 7)] = pack4(b0[j]);
    sSc[0][tid] = s0;
#pragma unroll
    for (int j = 0; j < 4; ++j) breg[j] = *(const int4*)(dwn32 + obj[j] + 32);
    sreg = dsc[scb + 2];
    sbar_all();
  }

  for (int s = 0; s < 16; ++s) {
    const int cur = s & 1;
    if (s < 15) {
#pragma unroll
      for (int i = 0; i < 8; ++i)
        glds16(act + aofs[i] + (uint32_t)(s + 1) * 64, &sA[cur ^ 1][(w * 64 + i * 8) * 64]);
#pragma unroll
      for (int j = 0; j < 4; ++j)
        sBp[cur ^ 1][((tid >> 3) + j * 32) * 9 + (tid & 7)] = pack4(breg[j]);
      sSc[cur ^ 1][tid] = sreg;
    }
    __builtin_amdgcn_sched_barrier(0);
    if (s < 14) {
#pragma unroll
      for (int j = 0; j < 4; ++j)
        breg[j] = *(const int4*)(dwn32 + obj[j] + (uint32_t)(s + 2) * 32);
      sreg = dsc[scb + (uint32_t)(s + 2) * 2];
    }
#pragma unroll
    for (int j = 0; j < 2; ++j) {
      const int xo = j ? x1 : x0;
      bf16x8 bf_[4];
#pragma unroll
      for (int t2 = 0; t2 < 4; ++t2)
        bf_[t2] = dqfrag(sBp[cur], sSc[cur], wc * 64 + t2 * 16 + c, j, q);
#pragma unroll
      for (int s4 = 0; s4 < 8; ++s4) {
        bf16x8 af = *(const bf16x8*)&sA[cur][(wr * 128 + s4 * 16 + c) * 64 + xo];
#pragma unroll
        for (int t2 = 0; t2 < 4; ++t2)
          Cd[s4][t2] = __builtin_amdgcn_mfma_f32_16x16x32_bf16(af, bf_[t2], Cd[s4][t2], 0, 0, 0);
      }
    }
    if (s < 14) sbar_cnt(); else sbar_all();
  }

  if (pout) {
#pragma unroll
    for (int s4 = 0; s4 < 8; ++s4) {
      const int mlb = wr * 128 + s4 * 16 + q * 4;
#pragma unroll
      for (int t2 = 0; t2 < 4; ++t2) {
        const int hg = h0 + wc * 64 + t2 * 16 + c;
#pragma unroll
        for (int r = 0; r < 4; ++r) {
          int prow = pidx_s[mlb + r];
          if (prow >= 0) pout[(size_t)prow * HD + hg] = Cd[s4][t2][r];
        }
      }
    }
  } else {
#pragma unroll
    for (int s4 = 0; s4 < 8; ++s4) {
      const int mlb = wr * 128 + s4 * 16 + q * 4;
#pragma unroll
      for (int t2 = 0; t2 < 4; ++t2) {
        const int hg = h0 + wc * 64 + t2 * 16 + c;
#pragma unroll
        for (int r = 0; r < 4; ++r) {
          int token = rows_s[mlb + r];
          if (token >= 0) atomicAdd(&out[(size_t)token * HD + hg], Cd[s4][t2][r]);
        }
      }
    }
  }
}

// out[t, :] = sum over the token's 4 pairs of pout[4t+k, :]. Fully coalesced.
__global__ void finalize_kernel(const float4* __restrict__ pout, float4* __restrict__ out) {
  int j = blockIdx.x * 256 + threadIdx.x;   // T*HD/4 = 1,048,576 float4s
  int token = j >> 9;                        // HD/4 = 512 float4 per row
  int col = j & 511;
  const float4* p = pout + ((size_t)token * 4) * 512 + col;
  float4 a = p[0], b = p[512], c = p[1024], d = p[1536];
  out[j] = float4{a.x + b.x + c.x + d.x, a.y + b.y + c.y + d.y,
                  a.z + b.z + c.z + d.z, a.w + b.w + c.w + d.w};
}

extern "C" void kernel_launch(void* const* d_in, const int* in_sizes, int n_in,
                              void* d_out, int out_size, void* d_ws, size_t ws_size,
                              hipStream_t stream) {
  const float* hidden = (const float*)d_in[0];
  const float* tw = (const float*)d_in[1];
  const int* ids = (const int*)d_in[2];
  const int* gup32 = (const int*)d_in[3];        // uint8 packed bytes, uploaded as int32
  const uint32_t* gus = (const uint32_t*)d_in[4];
  const int* dwn32 = (const int*)d_in[5];
  const uint32_t* dsc = (const uint32_t*)d_in[6];
  float* out = (float*)d_out;

  char* ws = (char*)d_ws;
  int* rows = (int*)(ws);                    // 48 KB
  float* rw = (float*)(ws + 49152);          // 48 KB
  int* te = (int*)(ws + 98304);              // 192 B
  u16* xb = (u16*)(ws + 131072);             // 8 MB
  u16* act = (u16*)(ws + 8519680);           // up to 25.2 MB (MAXT*BM rows)

  // Extended region (only touched if the workspace is big enough):
  const size_t POUT_OFF = 33685504ULL;       // act start + MAXT*BM*FD*2
  const size_t PIDX_OFF = POUT_OFF + (size_t)NPAIR * HD * 4;   // +67 MB
  const size_t WS_NEED = PIDX_OFF + (size_t)MAXT * BM * 4;
  const bool big = ws_size >= WS_NEED;
  float* pout = big ? (float*)(ws + POUT_OFF) : nullptr;
  int* pidx = big ? (int*)(ws + PIDX_OFF) : nullptr;

  cast_kernel<<<dim3(4096), dim3(256), 0, stream>>>(hidden, xb);
  if (!big) zero_kernel<<<dim3(4096), dim3(256), 0, stream>>>((float4*)out);
  route_kernel<<<dim3(1), dim3(256), 0, stream>>>(ids, tw, rows, rw, te, pidx);
  gemm1_kernel<<<dim3(16, MAXT), dim3(256), 0, stream>>>(xb, gup32, gus, rows, rw, te, act);
  gemm2_kernel<<<dim3(16, MAXT), dim3(256), 0, stream>>>(act, dwn32, dsc, rows, pidx, te, out, pout);
  if (big) finalize_kernel<<<dim3(1024 * 1024 / 256), dim3(256), 0, stream>>>((const float4*)pout, (float4*)out);
}